// Round 2
// baseline (1206.935 us; speedup 1.0000x reference)
//
#include <hip/hip_runtime.h>
#include <hip/hip_bf16.h>
#include <stdint.h>

#define S_NUM 50000
#define E_NUM 20000
#define NNODE 70000
#define KDIM 128
#define BATCH 8192
#define NEDGE 1000000

typedef __attribute__((ext_vector_type(8))) short short8;
typedef __attribute__((ext_vector_type(4))) float f32x4;

__device__ __forceinline__ float bf2f(ushort u) {
    union { uint32_t i; float f; } v; v.i = ((uint32_t)u) << 16; return v.f;
}
__device__ __forceinline__ ushort f2bf(float f) {
    union { uint32_t i; float f; } v; v.f = f;
    uint32_t r = v.i + 0x7fffu + ((v.i >> 16) & 1u);
    return (ushort)(r >> 16);
}

__global__ void zero_k(int* __restrict__ p, int n) {
    for (int i = blockIdx.x * blockDim.x + threadIdx.x; i < n; i += gridDim.x * blockDim.x)
        p[i] = 0;
}

// ---------------- histogram of dst ----------------
__global__ void hist_k(const int* __restrict__ dst, int* __restrict__ cnt) {
    for (int e = blockIdx.x * blockDim.x + threadIdx.x; e < NEDGE; e += gridDim.x * blockDim.x)
        atomicAdd(&cnt[dst[e]], 1);
}

// ---------------- single-block exclusive scan -> row_ptr, cursor ----------------
__global__ __launch_bounds__(1024) void scan_k(const int* __restrict__ cnt,
                                               int* __restrict__ rp, int* __restrict__ cur) {
    __shared__ int wsum[16];
    __shared__ int s_carry;
    int tid = threadIdx.x, lane = tid & 63, wid = tid >> 6;
    if (tid == 0) s_carry = 0;
    __syncthreads();
    for (int base = 0; base < NNODE; base += 1024) {
        int i = base + tid;
        int v = (i < NNODE) ? cnt[i] : 0;
        int incl = v;
        #pragma unroll
        for (int off = 1; off < 64; off <<= 1) {
            int t = __shfl_up(incl, off, 64);
            if (lane >= off) incl += t;
        }
        if (lane == 63) wsum[wid] = incl;
        __syncthreads();
        int carry = s_carry;
        if (wid == 0 && lane < 16) {
            int wv = wsum[lane];
            #pragma unroll
            for (int off = 1; off < 16; off <<= 1) {
                int t = __shfl_up(wv, off, 64);
                if (lane >= off) wv += t;
            }
            wsum[lane] = wv;
        }
        __syncthreads();
        int waveoff = (wid == 0) ? 0 : wsum[wid - 1];
        int excl = carry + waveoff + incl - v;
        if (i < NNODE) { rp[i] = excl; cur[i] = excl; }
        __syncthreads();
        if (tid == 0) s_carry = carry + wsum[15];
        __syncthreads();
    }
    if (threadIdx.x == 0) rp[NNODE] = s_carry;
}

// ---------------- CSR fill: bucket edges by dst ----------------
__global__ void fill_k(const int* __restrict__ src, const int* __restrict__ dst,
                       int* __restrict__ cur, int* __restrict__ csr) {
    for (int e = blockIdx.x * blockDim.x + threadIdx.x; e < NEDGE; e += gridDim.x * blockDim.x) {
        int d = dst[e];
        int slot = atomicAdd(&cur[d], 1);
        csr[slot] = src[e];
    }
}

// ---------------- GEMM: h = (feat @ W) * cj, f32 via bf16-split MFMA ----------------
// feat rows r<split come from a0, else a1 (layer 1 reads stu/exer directly).
// A·B = Ah·Bh + Ah·Bl + Al·Bh  (rel err ~2^-17).
// W (128x128 f32, row-major [k][c]) transposed to LDS Wt[c][k] hi/lo bf16 with
// 16B XOR swizzle (byte ^= (c&7)<<4) -> conflict-free ds_read_b128.
__global__ __launch_bounds__(256) void gemm_k(const float* __restrict__ a0,
                                              const float* __restrict__ a1, int split,
                                              const float* __restrict__ W,
                                              const float* __restrict__ cj,
                                              float* __restrict__ h) {
    __shared__ ushort wtHi[128 * 128];
    __shared__ ushort wtLo[128 * 128];
    {
        int t = threadIdx.x;
        for (int f = t; f < 4096; f += 256) {            // 4096 float4 = 16384 f32
            float4 v = ((const float4*)W)[f];
            int k = (f * 4) >> 7;
            int c0 = (f * 4) & 127;
            const float* pv = (const float*)&v;
            #pragma unroll
            for (int j = 0; j < 4; ++j) {
                int c = c0 + j;
                float x = pv[j];
                ushort hb = f2bf(x);
                ushort lb = f2bf(x - bf2f(hb));
                int idx = ((c * 256 + 2 * k) ^ ((c & 7) << 4)) >> 1;
                wtHi[idx] = hb;
                wtLo[idx] = lb;
            }
        }
    }
    __syncthreads();

    int wid = threadIdx.x >> 6, lane = threadIdx.x & 63;
    int rbase = blockIdx.x * 64 + wid * 16;
    if (rbase >= NNODE) return;

    int arow = rbase + (lane & 15);
    bool rok = arow < NNODE;
    const float* arp = (arow < split) ? a0 + (size_t)arow * KDIM
                                      : a1 + (size_t)(arow - split) * KDIM;
    int kq = (lane >> 4) * 8;          // k sub-offset for this lane group
    short8 aHi[4], aLo[4];
    #pragma unroll
    for (int kb = 0; kb < 4; ++kb) {
        #pragma unroll
        for (int j = 0; j < 8; ++j) {
            float x = rok ? arp[kb * 32 + kq + j] : 0.f;
            ushort hb = f2bf(x);
            aHi[kb][j] = (short)hb;
            aLo[kb][j] = (short)f2bf(x - bf2f(hb));
        }
    }
    int rq = (lane >> 4) * 4;          // output row sub-offset
    float cjv[4];
    #pragma unroll
    for (int b = 0; b < 4; ++b) {
        int r = rbase + rq + b;
        cjv[b] = (r < NNODE) ? cj[r] : 0.f;
    }
    #pragma unroll
    for (int cb = 0; cb < 8; ++cb) {
        f32x4 acc = {0.f, 0.f, 0.f, 0.f};
        #pragma unroll
        for (int kb = 0; kb < 4; ++kb) {
            int c = cb * 16 + (lane & 15);
            int byte = (c * 256 + 2 * (kb * 32 + kq)) ^ ((c & 7) << 4);
            short8 bHi = *(const short8*)((const char*)wtHi + byte);
            short8 bLo = *(const short8*)((const char*)wtLo + byte);
            acc = __builtin_amdgcn_mfma_f32_16x16x32_bf16(aHi[kb], bHi, acc, 0, 0, 0);
            acc = __builtin_amdgcn_mfma_f32_16x16x32_bf16(aHi[kb], bLo, acc, 0, 0, 0);
            acc = __builtin_amdgcn_mfma_f32_16x16x32_bf16(aLo[kb], bHi, acc, 0, 0, 0);
        }
        #pragma unroll
        for (int b = 0; b < 4; ++b) {
            int r = rbase + rq + b;
            if (r < NNODE)
                h[(size_t)r * KDIM + cb * 16 + (lane & 15)] = acc[b] * cjv[b];
        }
    }
}

// ---------------- aggregation: out[n] = ci[n] * sum_{e in CSR(n)} h[src_e] ----------------
// One wave per node; lane owns 2 f32 dims (8B) -> 512B coalesced row reads.
__global__ __launch_bounds__(256) void agg_k(const float* __restrict__ h,
                                             const int* __restrict__ rp,
                                             const int* __restrict__ csr,
                                             const float* __restrict__ ci,
                                             float* __restrict__ out) {
    int n = (blockIdx.x * blockDim.x + threadIdx.x) >> 6;
    int lane = threadIdx.x & 63;
    if (n >= NNODE) return;
    int beg = rp[n], end = rp[n + 1];
    float a0 = 0.f, a1 = 0.f;
    int e = beg;
    for (; e + 1 < end; e += 2) {                 // 2-deep to overlap gather latency
        int s0 = csr[e], s1 = csr[e + 1];
        float2 v0 = *(const float2*)(h + (size_t)s0 * KDIM + lane * 2);
        float2 v1 = *(const float2*)(h + (size_t)s1 * KDIM + lane * 2);
        a0 += v0.x + v1.x;
        a1 += v0.y + v1.y;
    }
    if (e < end) {
        int s = csr[e];
        float2 v = *(const float2*)(h + (size_t)s * KDIM + lane * 2);
        a0 += v.x; a1 += v.y;
    }
    float c = ci[n];
    float2 o; o.x = a0 * c; o.y = a1 * c;
    *(float2*)(out + (size_t)n * KDIM + lane * 2) = o;
}

// ---------------- output assembly (all f32) ----------------
__global__ void out_k(const float* __restrict__ w1, const float* __restrict__ w2,
                      const float* __restrict__ disc, const float* __restrict__ kn,
                      const int* __restrict__ sid, const int* __restrict__ eid,
                      float* __restrict__ out) {
    const int total = 2 * BATCH * KDIM + BATCH + KDIM * KDIM;
    for (int i = blockIdx.x * blockDim.x + threadIdx.x; i < total;
         i += gridDim.x * blockDim.x) {
        if (i < BATCH * KDIM) {
            int b = i >> 7, c = i & 127;
            size_t n = (size_t)sid[b];
            out[i] = w1[n * KDIM + c] + w2[n * KDIM + c];
        } else if (i < 2 * BATCH * KDIM) {
            int j = i - BATCH * KDIM;
            int b = j >> 7, c = j & 127;
            size_t n = (size_t)(S_NUM + eid[b]);
            out[i] = w1[n * KDIM + c] + w2[n * KDIM + c];
        } else if (i < 2 * BATCH * KDIM + BATCH) {
            out[i] = disc[eid[i - 2 * BATCH * KDIM]];
        } else {
            out[i] = kn[i - (2 * BATCH * KDIM + BATCH)];
        }
    }
}

static inline size_t align_up(size_t x) { return (x + 255) & ~(size_t)255; }

extern "C" void kernel_launch(void* const* d_in, const int* in_sizes, int n_in,
                              void* d_out, int out_size, void* d_ws, size_t ws_size,
                              hipStream_t stream) {
    const float* stu  = (const float*)d_in[0];
    const float* exer = (const float*)d_in[1];
    const float* kn   = (const float*)d_in[2];
    const float* disc = (const float*)d_in[3];
    const float* rW   = (const float*)d_in[4];
    const float* wW   = (const float*)d_in[5];
    const float* rci  = (const float*)d_in[6];
    const float* rcj  = (const float*)d_in[7];
    const float* wci  = (const float*)d_in[8];
    const float* wcj  = (const float*)d_in[9];
    const int* redge   = (const int*)d_in[10];
    const int* wedge   = (const int*)d_in[11];
    const int* sid     = (const int*)d_in[12];
    const int* eid     = (const int*)d_in[13];
    float* out         = (float*)d_out;

    char* p = (char*)d_ws;
    const size_t featB = align_up((size_t)NNODE * KDIM * 4);
    float* tA = (float*)p; p += featB;
    float* tB = (float*)p; p += featB;
    float* h  = (float*)p; p += featB;
    int* cnt = (int*)p; p += align_up((size_t)NNODE * 4);
    int* rp  = (int*)p; p += align_up((size_t)(NNODE + 1) * 4);
    int* cur = (int*)p; p += align_up((size_t)NNODE * 4);
    int* csr = (int*)p; p += align_up((size_t)NEDGE * 4);

    const int W_L = KDIM * KDIM;        // 16384 elems per layer weight
    const int gemmBlocks = (NNODE + 63) / 64;
    const int aggBlocks = (NNODE * 64 + 255) / 256;

    // ---- right graph ----
    zero_k<<<(NNODE + 255) / 256, 256, 0, stream>>>(cnt, NNODE);
    hist_k<<<2048, 256, 0, stream>>>(redge + NEDGE, cnt);
    scan_k<<<1, 1024, 0, stream>>>(cnt, rp, cur);
    fill_k<<<2048, 256, 0, stream>>>(redge, redge + NEDGE, cur, csr);

    gemm_k<<<gemmBlocks, 256, 0, stream>>>(stu, exer, S_NUM, rW + 0 * W_L, rcj, h);
    agg_k<<<aggBlocks, 256, 0, stream>>>(h, rp, csr, rci, tA);
    gemm_k<<<gemmBlocks, 256, 0, stream>>>(tA, tA, NNODE, rW + 1 * W_L, rcj, h);
    agg_k<<<aggBlocks, 256, 0, stream>>>(h, rp, csr, rci, tA);
    gemm_k<<<gemmBlocks, 256, 0, stream>>>(tA, tA, NNODE, rW + 2 * W_L, rcj, h);
    agg_k<<<aggBlocks, 256, 0, stream>>>(h, rp, csr, rci, tA);   // w1 = tA

    // ---- wrong graph ----
    zero_k<<<(NNODE + 255) / 256, 256, 0, stream>>>(cnt, NNODE);
    hist_k<<<2048, 256, 0, stream>>>(wedge + NEDGE, cnt);
    scan_k<<<1, 1024, 0, stream>>>(cnt, rp, cur);
    fill_k<<<2048, 256, 0, stream>>>(wedge, wedge + NEDGE, cur, csr);

    gemm_k<<<gemmBlocks, 256, 0, stream>>>(stu, exer, S_NUM, wW + 0 * W_L, wcj, h);
    agg_k<<<aggBlocks, 256, 0, stream>>>(h, rp, csr, wci, tB);
    gemm_k<<<gemmBlocks, 256, 0, stream>>>(tB, tB, NNODE, wW + 1 * W_L, wcj, h);
    agg_k<<<aggBlocks, 256, 0, stream>>>(h, rp, csr, wci, tB);
    gemm_k<<<gemmBlocks, 256, 0, stream>>>(tB, tB, NNODE, wW + 2 * W_L, wcj, h);
    agg_k<<<aggBlocks, 256, 0, stream>>>(h, rp, csr, wci, tB);   // w2 = tB

    out_k<<<2048, 256, 0, stream>>>(tA, tB, disc, kn, sid, eid, out);
}

// Round 3
// 1067.227 us; speedup vs baseline: 1.1309x; 1.1309x over previous
//
#include <hip/hip_runtime.h>
#include <hip/hip_bf16.h>
#include <stdint.h>

#define S_NUM 50000
#define E_NUM 20000
#define NNODE 70000
#define KDIM 128
#define BATCH 8192
#define NEDGE 1000000

typedef __attribute__((ext_vector_type(8))) short short8;
typedef __attribute__((ext_vector_type(4))) float f32x4;

__device__ __forceinline__ float bf2f(ushort u) {
    union { uint32_t i; float f; } v; v.i = ((uint32_t)u) << 16; return v.f;
}
__device__ __forceinline__ ushort f2bf(float f) {
    union { uint32_t i; float f; } v; v.f = f;
    uint32_t r = v.i + 0x7fffu + ((v.i >> 16) & 1u);
    return (ushort)(r >> 16);
}

__global__ void zero_k(int* __restrict__ p, int n) {
    for (int i = blockIdx.x * blockDim.x + threadIdx.x; i < n; i += gridDim.x * blockDim.x)
        p[i] = 0;
}

// ---------------- histogram of dst ----------------
__global__ void hist_k(const int* __restrict__ dst, int* __restrict__ cnt) {
    for (int e = blockIdx.x * blockDim.x + threadIdx.x; e < NEDGE; e += gridDim.x * blockDim.x)
        atomicAdd(&cnt[dst[e]], 1);
}

// ---------------- single-block exclusive scan -> row_ptr, cursor ----------------
__global__ __launch_bounds__(1024) void scan_k(const int* __restrict__ cnt,
                                               int* __restrict__ rp, int* __restrict__ cur) {
    __shared__ int wsum[16];
    __shared__ int s_carry;
    int tid = threadIdx.x, lane = tid & 63, wid = tid >> 6;
    if (tid == 0) s_carry = 0;
    __syncthreads();
    for (int base = 0; base < NNODE; base += 1024) {
        int i = base + tid;
        int v = (i < NNODE) ? cnt[i] : 0;
        int incl = v;
        #pragma unroll
        for (int off = 1; off < 64; off <<= 1) {
            int t = __shfl_up(incl, off, 64);
            if (lane >= off) incl += t;
        }
        if (lane == 63) wsum[wid] = incl;
        __syncthreads();
        int carry = s_carry;
        if (wid == 0 && lane < 16) {
            int wv = wsum[lane];
            #pragma unroll
            for (int off = 1; off < 16; off <<= 1) {
                int t = __shfl_up(wv, off, 64);
                if (lane >= off) wv += t;
            }
            wsum[lane] = wv;
        }
        __syncthreads();
        int waveoff = (wid == 0) ? 0 : wsum[wid - 1];
        int excl = carry + waveoff + incl - v;
        if (i < NNODE) { rp[i] = excl; cur[i] = excl; }
        __syncthreads();
        if (tid == 0) s_carry = carry + wsum[15];
        __syncthreads();
    }
    if (threadIdx.x == 0) rp[NNODE] = s_carry;
}

// ---------------- CSR fill: bucket edges by dst ----------------
__global__ void fill_k(const int* __restrict__ src, const int* __restrict__ dst,
                       int* __restrict__ cur, int* __restrict__ csr) {
    for (int e = blockIdx.x * blockDim.x + threadIdx.x; e < NEDGE; e += gridDim.x * blockDim.x) {
        int d = dst[e];
        int slot = atomicAdd(&cur[d], 1);
        csr[slot] = src[e];
    }
}

// ---------------- cvt: fc = bf16(cj ⊙ [stu; exer])  (layer-1 gather operand) ----------------
__global__ __launch_bounds__(256) void cvt_k(const float* __restrict__ stu,
                                             const float* __restrict__ exer,
                                             const float* __restrict__ cj,
                                             ushort* __restrict__ fc) {
    const int total = NNODE * 32;          // one float4 per thread-step
    for (int i = blockIdx.x * blockDim.x + threadIdx.x; i < total;
         i += gridDim.x * blockDim.x) {
        int node = i >> 5;
        int q = i & 31;
        const float* src = (node < S_NUM) ? stu + (size_t)node * KDIM
                                          : exer + (size_t)(node - S_NUM) * KDIM;
        float4 v = ((const float4*)src)[q];
        float c = cj[node];
        uint2 o;
        o.x = (uint32_t)f2bf(v.x * c) | ((uint32_t)f2bf(v.y * c) << 16);
        o.y = (uint32_t)f2bf(v.z * c) | ((uint32_t)f2bf(v.w * c) << 16);
        *(uint2*)(fc + (size_t)node * KDIM + q * 4) = o;
    }
}

// ---------------- aggregation: agg[n] = sum_{e in CSR(n)} fc[src_e]  (bf16 gather, f32 acc) ----
// One wave per node; lane owns 2 bf16 dims (4B) -> 256B coalesced row reads; 4-deep ILP.
__global__ __launch_bounds__(256) void agg_k(const uint32_t* __restrict__ fc,
                                             const int* __restrict__ rp,
                                             const int* __restrict__ csr,
                                             float* __restrict__ out) {
    int n = (blockIdx.x * blockDim.x + threadIdx.x) >> 6;
    int lane = threadIdx.x & 63;
    if (n >= NNODE) return;
    int beg = rp[n], end = rp[n + 1];
    float a0 = 0.f, a1 = 0.f;
    int e = beg;
    for (; e + 3 < end; e += 4) {
        int s0 = csr[e], s1 = csr[e + 1], s2 = csr[e + 2], s3 = csr[e + 3];
        uint32_t u0 = fc[(size_t)s0 * 64 + lane];
        uint32_t u1 = fc[(size_t)s1 * 64 + lane];
        uint32_t u2 = fc[(size_t)s2 * 64 + lane];
        uint32_t u3 = fc[(size_t)s3 * 64 + lane];
        a0 += bf2f((ushort)u0) + bf2f((ushort)u1) + bf2f((ushort)u2) + bf2f((ushort)u3);
        a1 += bf2f((ushort)(u0 >> 16)) + bf2f((ushort)(u1 >> 16)) +
              bf2f((ushort)(u2 >> 16)) + bf2f((ushort)(u3 >> 16));
    }
    for (; e < end; ++e) {
        uint32_t u = fc[(size_t)csr[e] * 64 + lane];
        a0 += bf2f((ushort)u);
        a1 += bf2f((ushort)(u >> 16));
    }
    float2 o; o.x = a0; o.y = a1;
    *(float2*)(out + (size_t)n * KDIM + lane * 2) = o;
}

// ---------------- GEMM: x = ci ⊙ (A @ W); write f32 (mode 0) or bf16(cj ⊙ x) (mode 1) -------
// A is f32 (agg output). bf16-split: A=Ah+Al, W=Wh+Wl; A·W ≈ Ah·Wh + Ah·Wl + Al·Wh.
// W transposed into LDS hi/lo with 16B XOR swizzle -> conflict-free ds_read_b128.
// In-place safe (outF==A): each wave loads its 16 A-rows into regs before writing them.
__global__ __launch_bounds__(256) void gemm_k(const float* __restrict__ A,
                                              const float* __restrict__ W,
                                              const float* __restrict__ ci,
                                              const float* __restrict__ cj,
                                              float* __restrict__ outF,
                                              ushort* __restrict__ outB,
                                              int mode) {
    __shared__ ushort wtHi[128 * 128];
    __shared__ ushort wtLo[128 * 128];
    {
        int t = threadIdx.x;
        for (int f = t; f < 4096; f += 256) {
            float4 v = ((const float4*)W)[f];
            int k = (f * 4) >> 7;
            int c0 = (f * 4) & 127;
            const float* pv = (const float*)&v;
            #pragma unroll
            for (int j = 0; j < 4; ++j) {
                int c = c0 + j;
                float x = pv[j];
                ushort hb = f2bf(x);
                ushort lb = f2bf(x - bf2f(hb));
                int idx = ((c * 256 + 2 * k) ^ ((c & 7) << 4)) >> 1;
                wtHi[idx] = hb;
                wtLo[idx] = lb;
            }
        }
    }
    __syncthreads();

    int wid = threadIdx.x >> 6, lane = threadIdx.x & 63;
    int rbase = blockIdx.x * 64 + wid * 16;
    if (rbase >= NNODE) return;

    int arow = rbase + (lane & 15);
    bool rok = arow < NNODE;
    int kq4 = (lane >> 4) * 2;             // float4 index of this lane's k-octet
    const float4* ar = (const float4*)(A + (size_t)arow * KDIM);
    float4 z4 = {0.f, 0.f, 0.f, 0.f};
    short8 aHi[4], aLo[4];
    #pragma unroll
    for (int kb = 0; kb < 4; ++kb) {
        float4 f0 = rok ? ar[kb * 8 + kq4] : z4;
        float4 f1 = rok ? ar[kb * 8 + kq4 + 1] : z4;
        const float* p0 = (const float*)&f0;
        const float* p1 = (const float*)&f1;
        #pragma unroll
        for (int j = 0; j < 4; ++j) {
            ushort hb = f2bf(p0[j]);
            aHi[kb][j] = (short)hb;
            aLo[kb][j] = (short)f2bf(p0[j] - bf2f(hb));
            ushort hb2 = f2bf(p1[j]);
            aHi[kb][j + 4] = (short)hb2;
            aLo[kb][j + 4] = (short)f2bf(p1[j] - bf2f(hb2));
        }
    }
    int rq = (lane >> 4) * 4;
    float scal[4];
    #pragma unroll
    for (int b = 0; b < 4; ++b) {
        int r = rbase + rq + b;
        scal[b] = (r < NNODE) ? (mode ? ci[r] * cj[r] : ci[r]) : 0.f;
    }
    #pragma unroll
    for (int cb = 0; cb < 8; ++cb) {
        f32x4 acc = {0.f, 0.f, 0.f, 0.f};
        #pragma unroll
        for (int kb = 0; kb < 4; ++kb) {
            int c = cb * 16 + (lane & 15);
            int byte = (c * 256 + 2 * (kb * 32 + (lane >> 4) * 8)) ^ ((c & 7) << 4);
            short8 bHi = *(const short8*)((const char*)wtHi + byte);
            short8 bLo = *(const short8*)((const char*)wtLo + byte);
            acc = __builtin_amdgcn_mfma_f32_16x16x32_bf16(aHi[kb], bHi, acc, 0, 0, 0);
            acc = __builtin_amdgcn_mfma_f32_16x16x32_bf16(aHi[kb], bLo, acc, 0, 0, 0);
            acc = __builtin_amdgcn_mfma_f32_16x16x32_bf16(aLo[kb], bHi, acc, 0, 0, 0);
        }
        int col = cb * 16 + (lane & 15);
        #pragma unroll
        for (int b = 0; b < 4; ++b) {
            int r = rbase + rq + b;
            if (r < NNODE) {
                float val = acc[b] * scal[b];
                if (mode) outB[(size_t)r * KDIM + col] = f2bf(val);
                else      outF[(size_t)r * KDIM + col] = val;
            }
        }
    }
}

// ---------------- output assembly (all f32) ----------------
__global__ void out_k(const float* __restrict__ w1, const float* __restrict__ w2,
                      const float* __restrict__ disc, const float* __restrict__ kn,
                      const int* __restrict__ sid, const int* __restrict__ eid,
                      float* __restrict__ out) {
    const int total = 2 * BATCH * KDIM + BATCH + KDIM * KDIM;
    for (int i = blockIdx.x * blockDim.x + threadIdx.x; i < total;
         i += gridDim.x * blockDim.x) {
        if (i < BATCH * KDIM) {
            int b = i >> 7, c = i & 127;
            size_t n = (size_t)sid[b];
            out[i] = w1[n * KDIM + c] + w2[n * KDIM + c];
        } else if (i < 2 * BATCH * KDIM) {
            int j = i - BATCH * KDIM;
            int b = j >> 7, c = j & 127;
            size_t n = (size_t)(S_NUM + eid[b]);
            out[i] = w1[n * KDIM + c] + w2[n * KDIM + c];
        } else if (i < 2 * BATCH * KDIM + BATCH) {
            out[i] = disc[eid[i - 2 * BATCH * KDIM]];
        } else {
            out[i] = kn[i - (2 * BATCH * KDIM + BATCH)];
        }
    }
}

static inline size_t align_up(size_t x) { return (x + 255) & ~(size_t)255; }

extern "C" void kernel_launch(void* const* d_in, const int* in_sizes, int n_in,
                              void* d_out, int out_size, void* d_ws, size_t ws_size,
                              hipStream_t stream) {
    const float* stu  = (const float*)d_in[0];
    const float* exer = (const float*)d_in[1];
    const float* kn   = (const float*)d_in[2];
    const float* disc = (const float*)d_in[3];
    const float* rW   = (const float*)d_in[4];
    const float* wW   = (const float*)d_in[5];
    const float* rci  = (const float*)d_in[6];
    const float* rcj  = (const float*)d_in[7];
    const float* wci  = (const float*)d_in[8];
    const float* wcj  = (const float*)d_in[9];
    const int* redge   = (const int*)d_in[10];
    const int* wedge   = (const int*)d_in[11];
    const int* sid     = (const int*)d_in[12];
    const int* eid     = (const int*)d_in[13];
    float* out         = (float*)d_out;

    char* p = (char*)d_ws;
    const size_t fB32 = align_up((size_t)NNODE * KDIM * 4);   // 35.84 MB
    const size_t fB16 = align_up((size_t)NNODE * KDIM * 2);   // 17.92 MB
    float*  aggb = (float*)p;  p += fB32;   // agg output; also w2 (in-place final gemm)
    float*  w1   = (float*)p;  p += fB32;
    ushort* fc   = (ushort*)p; p += fB16;   // bf16 cj-premultiplied features
    int* cnt = (int*)p; p += align_up((size_t)NNODE * 4);
    int* rp  = (int*)p; p += align_up((size_t)(NNODE + 1) * 4);
    int* cur = (int*)p; p += align_up((size_t)NNODE * 4);
    int* csr = (int*)p; p += align_up((size_t)NEDGE * 4);

    const int W_L = KDIM * KDIM;
    const int gemmBlocks = (NNODE + 63) / 64;
    const int aggBlocks = (NNODE * 64 + 255) / 256;

    // ---- right graph ----
    zero_k<<<(NNODE + 255) / 256, 256, 0, stream>>>(cnt, NNODE);
    hist_k<<<2048, 256, 0, stream>>>(redge + NEDGE, cnt);
    scan_k<<<1, 1024, 0, stream>>>(cnt, rp, cur);
    fill_k<<<2048, 256, 0, stream>>>(redge, redge + NEDGE, cur, csr);

    cvt_k<<<2048, 256, 0, stream>>>(stu, exer, rcj, fc);
    agg_k<<<aggBlocks, 256, 0, stream>>>((const uint32_t*)fc, rp, csr, aggb);
    gemm_k<<<gemmBlocks, 256, 0, stream>>>(aggb, rW + 0 * W_L, rci, rcj, nullptr, fc, 1);
    agg_k<<<aggBlocks, 256, 0, stream>>>((const uint32_t*)fc, rp, csr, aggb);
    gemm_k<<<gemmBlocks, 256, 0, stream>>>(aggb, rW + 1 * W_L, rci, rcj, nullptr, fc, 1);
    agg_k<<<aggBlocks, 256, 0, stream>>>((const uint32_t*)fc, rp, csr, aggb);
    gemm_k<<<gemmBlocks, 256, 0, stream>>>(aggb, rW + 2 * W_L, rci, rcj, w1, nullptr, 0);

    // ---- wrong graph ----
    zero_k<<<(NNODE + 255) / 256, 256, 0, stream>>>(cnt, NNODE);
    hist_k<<<2048, 256, 0, stream>>>(wedge + NEDGE, cnt);
    scan_k<<<1, 1024, 0, stream>>>(cnt, rp, cur);
    fill_k<<<2048, 256, 0, stream>>>(wedge, wedge + NEDGE, cur, csr);

    cvt_k<<<2048, 256, 0, stream>>>(stu, exer, wcj, fc);
    agg_k<<<aggBlocks, 256, 0, stream>>>((const uint32_t*)fc, rp, csr, aggb);
    gemm_k<<<gemmBlocks, 256, 0, stream>>>(aggb, wW + 0 * W_L, wci, wcj, nullptr, fc, 1);
    agg_k<<<aggBlocks, 256, 0, stream>>>((const uint32_t*)fc, rp, csr, aggb);
    gemm_k<<<gemmBlocks, 256, 0, stream>>>(aggb, wW + 1 * W_L, wci, wcj, nullptr, fc, 1);
    agg_k<<<aggBlocks, 256, 0, stream>>>((const uint32_t*)fc, rp, csr, aggb);
    gemm_k<<<gemmBlocks, 256, 0, stream>>>(aggb, wW + 2 * W_L, wci, wcj, aggb, nullptr, 0);

    out_k<<<2048, 256, 0, stream>>>(w1, aggb, disc, kn, sid, eid, out);
}

// Round 4
// 768.144 us; speedup vs baseline: 1.5712x; 1.3894x over previous
//
#include <hip/hip_runtime.h>
#include <hip/hip_bf16.h>
#include <stdint.h>

#define S_NUM 50000
#define E_NUM 20000
#define NNODE 70000
#define KDIM 128
#define BATCH 8192
#define NEDGE 1000000

typedef __attribute__((ext_vector_type(8))) short short8;
typedef __attribute__((ext_vector_type(4))) float f32x4;

__device__ __forceinline__ float bf2f(ushort u) {
    union { uint32_t i; float f; } v; v.i = ((uint32_t)u) << 16; return v.f;
}
__device__ __forceinline__ ushort f2bf(float f) {
    union { uint32_t i; float f; } v; v.f = f;
    uint32_t r = v.i + 0x7fffu + ((v.i >> 16) & 1u);
    return (ushort)(r >> 16);
}

__global__ void zero_k(int* __restrict__ p, int n) {
    for (int i = blockIdx.x * blockDim.x + threadIdx.x; i < n; i += gridDim.x * blockDim.x)
        p[i] = 0;
}

// ---------------- W prep: bf16 hi/lo split, transposed + 16B-XOR-swizzled layout -----------
// ws[m] = 64KB: hi plane [0,32KB), lo plane [32KB,64KB); byte off = ((c*256+2k)^((c&7)<<4)).
__global__ void prepW_k(const float* __restrict__ rW, const float* __restrict__ wW,
                        ushort* __restrict__ ws) {
    int i = blockIdx.x * blockDim.x + threadIdx.x;
    if (i >= 6 * 16384) return;
    int m = i >> 14, idx = i & 16383;
    const float* W = (m < 3) ? rW + m * 16384 : wW + (m - 3) * 16384;
    float x = W[idx];
    int k = idx >> 7, c = idx & 127;
    ushort hb = f2bf(x);
    ushort lb = f2bf(x - bf2f(hb));
    int off = ((c * 256 + 2 * k) ^ ((c & 7) << 4)) >> 1;
    ws[(size_t)m * 32768 + off] = hb;
    ws[(size_t)m * 32768 + 16384 + off] = lb;
}

// ---------------- both-graph histogram: 4 edges/thread, int4 loads ----------------
__global__ void hist2_k(const int* __restrict__ rdst, const int* __restrict__ wdst,
                        int* __restrict__ cnt) {
    int t = blockIdx.x * blockDim.x + threadIdx.x;
    const int TPG = NEDGE / 4;                 // 250000 threads per graph
    if (t >= 2 * TPG) return;
    const int* dst = (t < TPG) ? rdst : wdst;
    int* c = (t < TPG) ? cnt : cnt + NNODE;
    int e = ((t < TPG) ? t : t - TPG) * 4;
    int4 d = *(const int4*)(dst + e);
    atomicAdd(&c[d.x], 1);
    atomicAdd(&c[d.y], 1);
    atomicAdd(&c[d.z], 1);
    atomicAdd(&c[d.w], 1);
}

// ---------------- per-graph exclusive scan (blockIdx = graph) ----------------
__global__ __launch_bounds__(1024) void scan2_k(const int* __restrict__ cnt,
                                                int* __restrict__ rp, int* __restrict__ cur) {
    const int g = blockIdx.x;
    const int* c = cnt + (size_t)g * NNODE;
    int* rpg = rp + (size_t)g * (NNODE + 1);
    int* cg = cur + (size_t)g * NNODE;
    __shared__ int wsum[16];
    __shared__ int s_carry;
    int tid = threadIdx.x, lane = tid & 63, wid = tid >> 6;
    if (tid == 0) s_carry = 0;
    __syncthreads();
    for (int base = 0; base < NNODE; base += 1024) {
        int i = base + tid;
        int v = (i < NNODE) ? c[i] : 0;
        int incl = v;
        #pragma unroll
        for (int off = 1; off < 64; off <<= 1) {
            int t = __shfl_up(incl, off, 64);
            if (lane >= off) incl += t;
        }
        if (lane == 63) wsum[wid] = incl;
        __syncthreads();
        int carry = s_carry;
        if (wid == 0 && lane < 16) {
            int wv = wsum[lane];
            #pragma unroll
            for (int off = 1; off < 16; off <<= 1) {
                int t = __shfl_up(wv, off, 64);
                if (lane >= off) wv += t;
            }
            wsum[lane] = wv;
        }
        __syncthreads();
        int waveoff = (wid == 0) ? 0 : wsum[wid - 1];
        int excl = carry + waveoff + incl - v;
        if (i < NNODE) { rpg[i] = excl; cg[i] = excl; }
        __syncthreads();
        if (tid == 0) s_carry = carry + wsum[15];
        __syncthreads();
    }
    if (threadIdx.x == 0) rpg[NNODE] = s_carry;
}

// ---------------- both-graph CSR fill: 4 edges/thread, 4 independent atomic chains ---------
__global__ void fill2_k(const int* __restrict__ redge, const int* __restrict__ wedge,
                        int* __restrict__ cur, int* __restrict__ csr) {
    int t = blockIdx.x * blockDim.x + threadIdx.x;
    const int TPG = NEDGE / 4;
    if (t >= 2 * TPG) return;
    const int* eg = (t < TPG) ? redge : wedge;
    int* cg = (t < TPG) ? cur : cur + NNODE;
    int* og = (t < TPG) ? csr : csr + NEDGE;
    int e = ((t < TPG) ? t : t - TPG) * 4;
    int4 s = *(const int4*)(eg + e);
    int4 d = *(const int4*)(eg + NEDGE + e);
    int p0 = atomicAdd(&cg[d.x], 1);
    int p1 = atomicAdd(&cg[d.y], 1);
    int p2 = atomicAdd(&cg[d.z], 1);
    int p3 = atomicAdd(&cg[d.w], 1);
    og[p0] = s.x; og[p1] = s.y; og[p2] = s.z; og[p3] = s.w;
}

// ---------------- cvt: fc = bf16(cj ⊙ [stu; exer]) ----------------
__global__ __launch_bounds__(256) void cvt_k(const float* __restrict__ stu,
                                             const float* __restrict__ exer,
                                             const float* __restrict__ cj,
                                             ushort* __restrict__ fc) {
    const int total = NNODE * 32;
    for (int i = blockIdx.x * blockDim.x + threadIdx.x; i < total;
         i += gridDim.x * blockDim.x) {
        int node = i >> 5;
        int q = i & 31;
        const float* src = (node < S_NUM) ? stu + (size_t)node * KDIM
                                          : exer + (size_t)(node - S_NUM) * KDIM;
        float4 v = ((const float4*)src)[q];
        float c = cj[node];
        uint2 o;
        o.x = (uint32_t)f2bf(v.x * c) | ((uint32_t)f2bf(v.y * c) << 16);
        o.y = (uint32_t)f2bf(v.z * c) | ((uint32_t)f2bf(v.w * c) << 16);
        *(uint2*)(fc + (size_t)node * KDIM + q * 4) = o;
    }
}

// ---------------- aggregation: out[n] = bf16( sum_{e in CSR(n)} fc[src_e] ) ----------------
// One wave per node; lane owns 2 bf16 dims (4B) -> 256B coalesced rows; 4-deep ILP.
__global__ __launch_bounds__(256) void agg_k(const uint32_t* __restrict__ fc,
                                             const int* __restrict__ rp,
                                             const int* __restrict__ csr,
                                             uint32_t* __restrict__ out) {
    int n = (blockIdx.x * blockDim.x + threadIdx.x) >> 6;
    int lane = threadIdx.x & 63;
    if (n >= NNODE) return;
    int beg = rp[n], end = rp[n + 1];
    float a0 = 0.f, a1 = 0.f;
    int e = beg;
    for (; e + 3 < end; e += 4) {
        int s0 = csr[e], s1 = csr[e + 1], s2 = csr[e + 2], s3 = csr[e + 3];
        uint32_t u0 = fc[(size_t)s0 * 64 + lane];
        uint32_t u1 = fc[(size_t)s1 * 64 + lane];
        uint32_t u2 = fc[(size_t)s2 * 64 + lane];
        uint32_t u3 = fc[(size_t)s3 * 64 + lane];
        a0 += bf2f((ushort)u0) + bf2f((ushort)u1) + bf2f((ushort)u2) + bf2f((ushort)u3);
        a1 += bf2f((ushort)(u0 >> 16)) + bf2f((ushort)(u1 >> 16)) +
              bf2f((ushort)(u2 >> 16)) + bf2f((ushort)(u3 >> 16));
    }
    for (; e < end; ++e) {
        uint32_t u = fc[(size_t)csr[e] * 64 + lane];
        a0 += bf2f((ushort)u);
        a1 += bf2f((ushort)(u >> 16));
    }
    out[(size_t)n * 64 + lane] = (uint32_t)f2bf(a0) | ((uint32_t)f2bf(a1) << 16);
}

// ---------------- GEMM: out = bf16( scal ⊙ (A @ W) ), A bf16, W pre-split hi/lo ------------
// scal = ci (mode 0, final layer) or ci*cj (mode 1). A@W = A@Wh + A@Wl exactly (f32 acc).
__global__ __launch_bounds__(256) void gemm_k(const ushort* __restrict__ A,
                                              const ushort* __restrict__ wsm,
                                              const float* __restrict__ ci,
                                              const float* __restrict__ cj,
                                              ushort* __restrict__ outB,
                                              int mode) {
    __shared__ ushort wt[32768];   // 64 KB: hi plane + lo plane, pre-swizzled
    {
        const uint4* g = (const uint4*)wsm;
        uint4* l = (uint4*)wt;
        for (int i = threadIdx.x; i < 4096; i += 256) l[i] = g[i];
    }
    __syncthreads();

    int wid = threadIdx.x >> 6, lane = threadIdx.x & 63;
    int rbase = blockIdx.x * 64 + wid * 16;
    if (rbase >= NNODE) return;

    int arow = rbase + (lane & 15);
    bool rok = arow < NNODE;
    int q = lane >> 4;
    short8 z8 = {0, 0, 0, 0, 0, 0, 0, 0};
    const short8* ar = (const short8*)(A + (size_t)arow * KDIM);
    short8 afr[4];
    #pragma unroll
    for (int kb = 0; kb < 4; ++kb)
        afr[kb] = rok ? ar[kb * 4 + q] : z8;

    int rq = q * 4;
    float scal[4];
    #pragma unroll
    for (int b = 0; b < 4; ++b) {
        int r = rbase + rq + b;
        scal[b] = (r < NNODE) ? (mode ? ci[r] * cj[r] : ci[r]) : 0.f;
    }
    #pragma unroll
    for (int cb = 0; cb < 8; ++cb) {
        f32x4 acc = {0.f, 0.f, 0.f, 0.f};
        int c = cb * 16 + (lane & 15);
        #pragma unroll
        for (int kb = 0; kb < 4; ++kb) {
            int byte = (c * 256 + 2 * (kb * 32 + q * 8)) ^ ((c & 7) << 4);
            short8 bHi = *(const short8*)((const char*)wt + byte);
            short8 bLo = *(const short8*)((const char*)wt + 32768 + byte);
            acc = __builtin_amdgcn_mfma_f32_16x16x32_bf16(afr[kb], bHi, acc, 0, 0, 0);
            acc = __builtin_amdgcn_mfma_f32_16x16x32_bf16(afr[kb], bLo, acc, 0, 0, 0);
        }
        #pragma unroll
        for (int b = 0; b < 4; ++b) {
            int r = rbase + rq + b;
            if (r < NNODE)
                outB[(size_t)r * KDIM + c] = f2bf(acc[b] * scal[b]);
        }
    }
}

// ---------------- output assembly (w1/w2 bf16 -> f32 out) ----------------
__global__ void out_k(const ushort* __restrict__ w1, const ushort* __restrict__ w2,
                      const float* __restrict__ disc, const float* __restrict__ kn,
                      const int* __restrict__ sid, const int* __restrict__ eid,
                      float* __restrict__ out) {
    const int total = 2 * BATCH * KDIM + BATCH + KDIM * KDIM;
    for (int i = blockIdx.x * blockDim.x + threadIdx.x; i < total;
         i += gridDim.x * blockDim.x) {
        if (i < BATCH * KDIM) {
            int b = i >> 7, c = i & 127;
            size_t n = (size_t)sid[b];
            out[i] = bf2f(w1[n * KDIM + c]) + bf2f(w2[n * KDIM + c]);
        } else if (i < 2 * BATCH * KDIM) {
            int j = i - BATCH * KDIM;
            int b = j >> 7, c = j & 127;
            size_t n = (size_t)(S_NUM + eid[b]);
            out[i] = bf2f(w1[n * KDIM + c]) + bf2f(w2[n * KDIM + c]);
        } else if (i < 2 * BATCH * KDIM + BATCH) {
            out[i] = disc[eid[i - 2 * BATCH * KDIM]];
        } else {
            out[i] = kn[i - (2 * BATCH * KDIM + BATCH)];
        }
    }
}

static inline size_t align_up(size_t x) { return (x + 255) & ~(size_t)255; }

extern "C" void kernel_launch(void* const* d_in, const int* in_sizes, int n_in,
                              void* d_out, int out_size, void* d_ws, size_t ws_size,
                              hipStream_t stream) {
    const float* stu  = (const float*)d_in[0];
    const float* exer = (const float*)d_in[1];
    const float* kn   = (const float*)d_in[2];
    const float* disc = (const float*)d_in[3];
    const float* rW   = (const float*)d_in[4];
    const float* wW   = (const float*)d_in[5];
    const float* rci  = (const float*)d_in[6];
    const float* rcj  = (const float*)d_in[7];
    const float* wci  = (const float*)d_in[8];
    const float* wcj  = (const float*)d_in[9];
    const int* redge   = (const int*)d_in[10];
    const int* wedge   = (const int*)d_in[11];
    const int* sid     = (const int*)d_in[12];
    const int* eid     = (const int*)d_in[13];
    float* out         = (float*)d_out;

    char* p = (char*)d_ws;
    const size_t fB16 = align_up((size_t)NNODE * KDIM * 2);   // 17.92 MB
    ushort* fcA = (ushort*)p; p += fB16;
    ushort* fcB = (ushort*)p; p += fB16;
    ushort* w1  = (ushort*)p; p += fB16;
    ushort* w2  = (ushort*)p; p += fB16;
    ushort* ws  = (ushort*)p; p += align_up((size_t)6 * 32768 * 2);   // 384 KB
    int* cnt = (int*)p; p += align_up((size_t)2 * NNODE * 4);
    int* rp  = (int*)p; p += align_up((size_t)2 * (NNODE + 1) * 4);
    int* cur = (int*)p; p += align_up((size_t)2 * NNODE * 4);
    int* csr = (int*)p; p += align_up((size_t)2 * NEDGE * 4);

    const int gemmBlocks = (NNODE + 63) / 64;
    const int aggBlocks = (NNODE * 64 + 255) / 256;
    const int edgeBlocks = (2 * (NEDGE / 4) + 255) / 256;

    // ---- shared prep: W split + both CSRs ----
    prepW_k<<<(6 * 16384 + 255) / 256, 256, 0, stream>>>(rW, wW, ws);
    zero_k<<<(2 * NNODE + 255) / 256, 256, 0, stream>>>(cnt, 2 * NNODE);
    hist2_k<<<edgeBlocks, 256, 0, stream>>>(redge + NEDGE, wedge + NEDGE, cnt);
    scan2_k<<<2, 1024, 0, stream>>>(cnt, rp, cur);
    fill2_k<<<edgeBlocks, 256, 0, stream>>>(redge, wedge, cur, csr);

    const int* rp1 = rp;
    const int* rp2 = rp + (NNODE + 1);
    const int* csr1 = csr;
    const int* csr2 = csr + NEDGE;

    // ---- right graph ----
    cvt_k<<<2048, 256, 0, stream>>>(stu, exer, rcj, fcA);
    agg_k<<<aggBlocks, 256, 0, stream>>>((const uint32_t*)fcA, rp1, csr1, (uint32_t*)fcB);
    gemm_k<<<gemmBlocks, 256, 0, stream>>>(fcB, ws + 0 * 32768, rci, rcj, fcA, 1);
    agg_k<<<aggBlocks, 256, 0, stream>>>((const uint32_t*)fcA, rp1, csr1, (uint32_t*)fcB);
    gemm_k<<<gemmBlocks, 256, 0, stream>>>(fcB, ws + 1 * 32768, rci, rcj, fcA, 1);
    agg_k<<<aggBlocks, 256, 0, stream>>>((const uint32_t*)fcA, rp1, csr1, (uint32_t*)fcB);
    gemm_k<<<gemmBlocks, 256, 0, stream>>>(fcB, ws + 2 * 32768, rci, rcj, w1, 0);

    // ---- wrong graph ----
    cvt_k<<<2048, 256, 0, stream>>>(stu, exer, wcj, fcA);
    agg_k<<<aggBlocks, 256, 0, stream>>>((const uint32_t*)fcA, rp2, csr2, (uint32_t*)fcB);
    gemm_k<<<gemmBlocks, 256, 0, stream>>>(fcB, ws + 3 * 32768, wci, wcj, fcA, 1);
    agg_k<<<aggBlocks, 256, 0, stream>>>((const uint32_t*)fcA, rp2, csr2, (uint32_t*)fcB);
    gemm_k<<<gemmBlocks, 256, 0, stream>>>(fcB, ws + 4 * 32768, wci, wcj, fcA, 1);
    agg_k<<<aggBlocks, 256, 0, stream>>>((const uint32_t*)fcA, rp2, csr2, (uint32_t*)fcB);
    gemm_k<<<gemmBlocks, 256, 0, stream>>>(fcB, ws + 5 * 32768, wci, wcj, w2, 0);

    out_k<<<2048, 256, 0, stream>>>(w1, w2, disc, kn, sid, eid, out);
}

// Round 5
// 680.868 us; speedup vs baseline: 1.7726x; 1.1282x over previous
//
#include <hip/hip_runtime.h>
#include <hip/hip_bf16.h>
#include <stdint.h>

#define S_NUM 50000
#define E_NUM 20000
#define NNODE 70000
#define KDIM 128
#define BATCH 8192
#define NEDGE 1000000

typedef __attribute__((ext_vector_type(8))) short short8;
typedef __attribute__((ext_vector_type(4))) float f32x4;

__device__ __forceinline__ float bf2f(ushort u) {
    union { uint32_t i; float f; } v; v.i = ((uint32_t)u) << 16; return v.f;
}
__device__ __forceinline__ ushort f2bf(float f) {
    union { uint32_t i; float f; } v; v.f = f;
    uint32_t r = v.i + 0x7fffu + ((v.i >> 16) & 1u);
    return (ushort)(r >> 16);
}

__global__ void zero_k(int* __restrict__ p, int n) {
    for (int i = blockIdx.x * blockDim.x + threadIdx.x; i < n; i += gridDim.x * blockDim.x)
        p[i] = 0;
}

// ---------------- W prep: bf16 hi/lo split, transposed + 16B-XOR-swizzled layout -----------
__global__ void prepW_k(const float* __restrict__ rW, const float* __restrict__ wW,
                        ushort* __restrict__ ws) {
    int i = blockIdx.x * blockDim.x + threadIdx.x;
    if (i >= 6 * 16384) return;
    int m = i >> 14, idx = i & 16383;
    const float* W = (m < 3) ? rW + m * 16384 : wW + (m - 3) * 16384;
    float x = W[idx];
    int k = idx >> 7, c = idx & 127;
    ushort hb = f2bf(x);
    ushort lb = f2bf(x - bf2f(hb));
    int off = ((c * 256 + 2 * k) ^ ((c & 7) << 4)) >> 1;
    ws[(size_t)m * 32768 + off] = hb;
    ws[(size_t)m * 32768 + 16384 + off] = lb;
}

// ---------------- dst-partitioned histogram ----------------
// combo = blockIdx&7: range-quarter (combo&3) x graph (combo>>2). Each combo's blocks
// stream the whole dst array; atomics land in one XCD-local 70KB cnt slice.
__global__ __launch_bounds__(256) void hist_part_k(const int* __restrict__ rdst,
                                                   const int* __restrict__ wdst,
                                                   int* __restrict__ cnt) {
    int bid = blockIdx.x;
    int grp = bid & 3, graph = (bid >> 2) & 1;
    int lo = grp * 17500, hi = lo + 17500;
    const int4* d4 = (const int4*)(graph ? wdst : rdst);
    int* c = cnt + graph * NNODE;
    const int NI4 = NEDGE / 4;                       // 250000
    for (int i = (bid >> 3) * 256 + threadIdx.x; i < NI4; i += 128 * 256) {
        int4 d = d4[i];
        if (d.x >= lo && d.x < hi) atomicAdd(&c[d.x], 1);
        if (d.y >= lo && d.y < hi) atomicAdd(&c[d.y], 1);
        if (d.z >= lo && d.z < hi) atomicAdd(&c[d.z], 1);
        if (d.w >= lo && d.w < hi) atomicAdd(&c[d.w], 1);
    }
}

// ---------------- per-graph exclusive scan (blockIdx = graph) ----------------
__global__ __launch_bounds__(1024) void scan2_k(const int* __restrict__ cnt,
                                                int* __restrict__ rp, int* __restrict__ cur) {
    const int g = blockIdx.x;
    const int* c = cnt + (size_t)g * NNODE;
    int* rpg = rp + (size_t)g * (NNODE + 1);
    int* cg = cur + (size_t)g * NNODE;
    __shared__ int wsum[16];
    __shared__ int s_carry;
    int tid = threadIdx.x, lane = tid & 63, wid = tid >> 6;
    if (tid == 0) s_carry = 0;
    __syncthreads();
    for (int base = 0; base < NNODE; base += 1024) {
        int i = base + tid;
        int v = (i < NNODE) ? c[i] : 0;
        int incl = v;
        #pragma unroll
        for (int off = 1; off < 64; off <<= 1) {
            int t = __shfl_up(incl, off, 64);
            if (lane >= off) incl += t;
        }
        if (lane == 63) wsum[wid] = incl;
        __syncthreads();
        int carry = s_carry;
        if (wid == 0 && lane < 16) {
            int wv = wsum[lane];
            #pragma unroll
            for (int off = 1; off < 16; off <<= 1) {
                int t = __shfl_up(wv, off, 64);
                if (lane >= off) wv += t;
            }
            wsum[lane] = wv;
        }
        __syncthreads();
        int waveoff = (wid == 0) ? 0 : wsum[wid - 1];
        int excl = carry + waveoff + incl - v;
        if (i < NNODE) { rpg[i] = excl; cg[i] = excl; }
        __syncthreads();
        if (tid == 0) s_carry = carry + wsum[15];
        __syncthreads();
    }
    if (threadIdx.x == 0) rpg[NNODE] = s_carry;
}

// ---------------- dst-partitioned CSR fill ----------------
// combo = blockIdx&15: range-eighth (combo&7) x graph (combo>>3). XCD = blockIdx%8 =
// range group -> each XCD's csr write window is the contiguous rp-slice of its dst
// range (~1MB) -> L2-resident, full-line evictions (was 139MB HBM writes).
__global__ __launch_bounds__(256) void fill_part_k(const int* __restrict__ redge,
                                                   const int* __restrict__ wedge,
                                                   int* __restrict__ cur,
                                                   int* __restrict__ csr) {
    int bid = blockIdx.x;
    int grp = bid & 7, graph = (bid >> 3) & 1;
    int lo = grp * 8750, hi = lo + 8750;
    const int* eg = graph ? wedge : redge;
    const int4* s4 = (const int4*)eg;
    const int4* d4 = (const int4*)(eg + NEDGE);
    int* cg = cur + graph * NNODE;
    int* og = csr + graph * NEDGE;
    const int NI4 = NEDGE / 4;
    for (int i = (bid >> 4) * 256 + threadIdx.x; i < NI4; i += 64 * 256) {
        int4 d = d4[i];
        int4 s = s4[i];
        if (d.x >= lo && d.x < hi) og[atomicAdd(&cg[d.x], 1)] = s.x;
        if (d.y >= lo && d.y < hi) og[atomicAdd(&cg[d.y], 1)] = s.y;
        if (d.z >= lo && d.z < hi) og[atomicAdd(&cg[d.z], 1)] = s.z;
        if (d.w >= lo && d.w < hi) og[atomicAdd(&cg[d.w], 1)] = s.w;
    }
}

// ---------------- cvt both graphs: fcR = bf16(rcj ⊙ feat), fcW = bf16(wcj ⊙ feat) ----------
__global__ __launch_bounds__(256) void cvt2_k(const float* __restrict__ stu,
                                              const float* __restrict__ exer,
                                              const float* __restrict__ rcj,
                                              const float* __restrict__ wcj,
                                              ushort* __restrict__ fcR,
                                              ushort* __restrict__ fcW) {
    const int total = NNODE * 32;
    for (int i = blockIdx.x * blockDim.x + threadIdx.x; i < total;
         i += gridDim.x * blockDim.x) {
        int node = i >> 5;
        int q = i & 31;
        const float* src = (node < S_NUM) ? stu + (size_t)node * KDIM
                                          : exer + (size_t)(node - S_NUM) * KDIM;
        float4 v = ((const float4*)src)[q];
        float cr = rcj[node], cw = wcj[node];
        uint2 oR, oW;
        oR.x = (uint32_t)f2bf(v.x * cr) | ((uint32_t)f2bf(v.y * cr) << 16);
        oR.y = (uint32_t)f2bf(v.z * cr) | ((uint32_t)f2bf(v.w * cr) << 16);
        oW.x = (uint32_t)f2bf(v.x * cw) | ((uint32_t)f2bf(v.y * cw) << 16);
        oW.y = (uint32_t)f2bf(v.z * cw) | ((uint32_t)f2bf(v.w * cw) << 16);
        *(uint2*)(fcR + (size_t)node * KDIM + q * 4) = oR;
        *(uint2*)(fcW + (size_t)node * KDIM + q * 4) = oW;
    }
}

// ---------------- aggregation: out[n] = bf16( sum_{e in CSR(n)} fc[src_e] ) ----------------
__global__ __launch_bounds__(256) void agg_k(const uint32_t* __restrict__ fc,
                                             const int* __restrict__ rp,
                                             const int* __restrict__ csr,
                                             uint32_t* __restrict__ out) {
    int n = (blockIdx.x * blockDim.x + threadIdx.x) >> 6;
    int lane = threadIdx.x & 63;
    if (n >= NNODE) return;
    int beg = rp[n], end = rp[n + 1];
    float a0 = 0.f, a1 = 0.f;
    int e = beg;
    for (; e + 3 < end; e += 4) {
        int s0 = csr[e], s1 = csr[e + 1], s2 = csr[e + 2], s3 = csr[e + 3];
        uint32_t u0 = fc[(size_t)s0 * 64 + lane];
        uint32_t u1 = fc[(size_t)s1 * 64 + lane];
        uint32_t u2 = fc[(size_t)s2 * 64 + lane];
        uint32_t u3 = fc[(size_t)s3 * 64 + lane];
        a0 += bf2f((ushort)u0) + bf2f((ushort)u1) + bf2f((ushort)u2) + bf2f((ushort)u3);
        a1 += bf2f((ushort)(u0 >> 16)) + bf2f((ushort)(u1 >> 16)) +
              bf2f((ushort)(u2 >> 16)) + bf2f((ushort)(u3 >> 16));
    }
    for (; e < end; ++e) {
        uint32_t u = fc[(size_t)csr[e] * 64 + lane];
        a0 += bf2f((ushort)u);
        a1 += bf2f((ushort)(u >> 16));
    }
    out[(size_t)n * 64 + lane] = (uint32_t)f2bf(a0) | ((uint32_t)f2bf(a1) << 16);
}

// ---------------- GEMM: out = bf16( scal ⊙ (A @ W) ), A bf16, W pre-split hi/lo ------------
__global__ __launch_bounds__(256) void gemm_k(const ushort* __restrict__ A,
                                              const ushort* __restrict__ wsm,
                                              const float* __restrict__ ci,
                                              const float* __restrict__ cj,
                                              ushort* __restrict__ outB,
                                              int mode) {
    __shared__ ushort wt[32768];   // 64 KB: hi plane + lo plane, pre-swizzled
    {
        const uint4* g = (const uint4*)wsm;
        uint4* l = (uint4*)wt;
        for (int i = threadIdx.x; i < 4096; i += 256) l[i] = g[i];
    }
    __syncthreads();

    int wid = threadIdx.x >> 6, lane = threadIdx.x & 63;
    int rbase = blockIdx.x * 64 + wid * 16;
    if (rbase >= NNODE) return;

    int arow = rbase + (lane & 15);
    bool rok = arow < NNODE;
    int q = lane >> 4;
    short8 z8 = {0, 0, 0, 0, 0, 0, 0, 0};
    const short8* ar = (const short8*)(A + (size_t)arow * KDIM);
    short8 afr[4];
    #pragma unroll
    for (int kb = 0; kb < 4; ++kb)
        afr[kb] = rok ? ar[kb * 4 + q] : z8;

    int rq = q * 4;
    float scal[4];
    #pragma unroll
    for (int b = 0; b < 4; ++b) {
        int r = rbase + rq + b;
        scal[b] = (r < NNODE) ? (mode ? ci[r] * cj[r] : ci[r]) : 0.f;
    }
    #pragma unroll
    for (int cb = 0; cb < 8; ++cb) {
        f32x4 acc = {0.f, 0.f, 0.f, 0.f};
        int c = cb * 16 + (lane & 15);
        #pragma unroll
        for (int kb = 0; kb < 4; ++kb) {
            int byte = (c * 256 + 2 * (kb * 32 + q * 8)) ^ ((c & 7) << 4);
            short8 bHi = *(const short8*)((const char*)wt + byte);
            short8 bLo = *(const short8*)((const char*)wt + 32768 + byte);
            acc = __builtin_amdgcn_mfma_f32_16x16x32_bf16(afr[kb], bHi, acc, 0, 0, 0);
            acc = __builtin_amdgcn_mfma_f32_16x16x32_bf16(afr[kb], bLo, acc, 0, 0, 0);
        }
        #pragma unroll
        for (int b = 0; b < 4; ++b) {
            int r = rbase + rq + b;
            if (r < NNODE)
                outB[(size_t)r * KDIM + c] = f2bf(acc[b] * scal[b]);
        }
    }
}

// ---------------- output assembly (w1/w2 bf16 -> f32 out) ----------------
__global__ void out_k(const ushort* __restrict__ w1, const ushort* __restrict__ w2,
                      const float* __restrict__ disc, const float* __restrict__ kn,
                      const int* __restrict__ sid, const int* __restrict__ eid,
                      float* __restrict__ out) {
    const int total = 2 * BATCH * KDIM + BATCH + KDIM * KDIM;
    for (int i = blockIdx.x * blockDim.x + threadIdx.x; i < total;
         i += gridDim.x * blockDim.x) {
        if (i < BATCH * KDIM) {
            int b = i >> 7, c = i & 127;
            size_t n = (size_t)sid[b];
            out[i] = bf2f(w1[n * KDIM + c]) + bf2f(w2[n * KDIM + c]);
        } else if (i < 2 * BATCH * KDIM) {
            int j = i - BATCH * KDIM;
            int b = j >> 7, c = j & 127;
            size_t n = (size_t)(S_NUM + eid[b]);
            out[i] = bf2f(w1[n * KDIM + c]) + bf2f(w2[n * KDIM + c]);
        } else if (i < 2 * BATCH * KDIM + BATCH) {
            out[i] = disc[eid[i - 2 * BATCH * KDIM]];
        } else {
            out[i] = kn[i - (2 * BATCH * KDIM + BATCH)];
        }
    }
}

static inline size_t align_up(size_t x) { return (x + 255) & ~(size_t)255; }

extern "C" void kernel_launch(void* const* d_in, const int* in_sizes, int n_in,
                              void* d_out, int out_size, void* d_ws, size_t ws_size,
                              hipStream_t stream) {
    const float* stu  = (const float*)d_in[0];
    const float* exer = (const float*)d_in[1];
    const float* kn   = (const float*)d_in[2];
    const float* disc = (const float*)d_in[3];
    const float* rW   = (const float*)d_in[4];
    const float* wW   = (const float*)d_in[5];
    const float* rci  = (const float*)d_in[6];
    const float* rcj  = (const float*)d_in[7];
    const float* wci  = (const float*)d_in[8];
    const float* wcj  = (const float*)d_in[9];
    const int* redge   = (const int*)d_in[10];
    const int* wedge   = (const int*)d_in[11];
    const int* sid     = (const int*)d_in[12];
    const int* eid     = (const int*)d_in[13];
    float* out         = (float*)d_out;

    char* p = (char*)d_ws;
    const size_t fB16 = align_up((size_t)NNODE * KDIM * 2);   // 17.92 MB
    ushort* fcR = (ushort*)p; p += fB16;
    ushort* fcW = (ushort*)p; p += fB16;
    ushort* pA  = (ushort*)p; p += fB16;
    ushort* w1  = (ushort*)p; p += fB16;
    ushort* w2  = (ushort*)p; p += fB16;
    ushort* ws  = (ushort*)p; p += align_up((size_t)6 * 32768 * 2);   // 384 KB
    int* cnt = (int*)p; p += align_up((size_t)2 * NNODE * 4);
    int* rp  = (int*)p; p += align_up((size_t)2 * (NNODE + 1) * 4);
    int* cur = (int*)p; p += align_up((size_t)2 * NNODE * 4);
    int* csr = (int*)p; p += align_up((size_t)2 * NEDGE * 4);

    const int gemmBlocks = (NNODE + 63) / 64;
    const int aggBlocks = (NNODE * 64 + 255) / 256;

    // ---- shared prep: W split + both CSRs ----
    prepW_k<<<(6 * 16384 + 255) / 256, 256, 0, stream>>>(rW, wW, ws);
    zero_k<<<(2 * NNODE + 255) / 256, 256, 0, stream>>>(cnt, 2 * NNODE);
    hist_part_k<<<1024, 256, 0, stream>>>(redge + NEDGE, wedge + NEDGE, cnt);
    scan2_k<<<2, 1024, 0, stream>>>(cnt, rp, cur);
    fill_part_k<<<1024, 256, 0, stream>>>(redge, wedge, cur, csr);
    cvt2_k<<<2048, 256, 0, stream>>>(stu, exer, rcj, wcj, fcR, fcW);

    const int* rp1 = rp;
    const int* rp2 = rp + (NNODE + 1);
    const int* csr1 = csr;
    const int* csr2 = csr + NEDGE;

    // ---- right graph ----
    agg_k<<<aggBlocks, 256, 0, stream>>>((const uint32_t*)fcR, rp1, csr1, (uint32_t*)pA);
    gemm_k<<<gemmBlocks, 256, 0, stream>>>(pA, ws + 0 * 32768, rci, rcj, fcR, 1);
    agg_k<<<aggBlocks, 256, 0, stream>>>((const uint32_t*)fcR, rp1, csr1, (uint32_t*)pA);
    gemm_k<<<gemmBlocks, 256, 0, stream>>>(pA, ws + 1 * 32768, rci, rcj, fcR, 1);
    agg_k<<<aggBlocks, 256, 0, stream>>>((const uint32_t*)fcR, rp1, csr1, (uint32_t*)pA);
    gemm_k<<<gemmBlocks, 256, 0, stream>>>(pA, ws + 2 * 32768, rci, rcj, w1, 0);

    // ---- wrong graph ----
    agg_k<<<aggBlocks, 256, 0, stream>>>((const uint32_t*)fcW, rp2, csr2, (uint32_t*)pA);
    gemm_k<<<gemmBlocks, 256, 0, stream>>>(pA, ws + 3 * 32768, wci, wcj, fcW, 1);
    agg_k<<<aggBlocks, 256, 0, stream>>>((const uint32_t*)fcW, rp2, csr2, (uint32_t*)pA);
    gemm_k<<<gemmBlocks, 256, 0, stream>>>(pA, ws + 4 * 32768, wci, wcj, fcW, 1);
    agg_k<<<aggBlocks, 256, 0, stream>>>((const uint32_t*)fcW, rp2, csr2, (uint32_t*)pA);
    gemm_k<<<gemmBlocks, 256, 0, stream>>>(pA, ws + 5 * 32768, wci, wcj, w2, 0);

    out_k<<<2048, 256, 0, stream>>>(w1, w2, disc, kn, sid, eid, out);
}

// Round 6
// 612.924 us; speedup vs baseline: 1.9691x; 1.1109x over previous
//
#include <hip/hip_runtime.h>
#include <hip/hip_bf16.h>
#include <stdint.h>

#define S_NUM 50000
#define E_NUM 20000
#define NNODE 70000
#define KDIM 128
#define BATCH 8192
#define NEDGE 1000000

#define RANGE 8750            // NNODE / 8 dst-ranges
#define CHUNK 2048            // edges per bucket_k block
#define BCAP 560              // LDS bin capacity (mean 256, 20 sigma)
#define BUCKET_CAP 131072     // global per-bucket capacity (mean 125K, 18 sigma)

typedef __attribute__((ext_vector_type(8))) short short8;
typedef __attribute__((ext_vector_type(4))) float f32x4;

__device__ __forceinline__ float bf2f(ushort u) {
    union { uint32_t i; float f; } v; v.i = ((uint32_t)u) << 16; return v.f;
}
__device__ __forceinline__ ushort f2bf(float f) {
    union { uint32_t i; float f; } v; v.f = f;
    uint32_t r = v.i + 0x7fffu + ((v.i >> 16) & 1u);
    return (ushort)(r >> 16);
}
__device__ __forceinline__ float hi2f(uint32_t u) {
    union { uint32_t i; float f; } v; v.i = u & 0xffff0000u; return v.f;
}
__device__ __forceinline__ float lo2f(uint32_t u) {
    union { uint32_t i; float f; } v; v.i = u << 16; return v.f;
}

__global__ void zero_k(int* __restrict__ p, int n) {
    for (int i = blockIdx.x * blockDim.x + threadIdx.x; i < n; i += gridDim.x * blockDim.x)
        p[i] = 0;
}

// ---------------- W prep: bf16 hi/lo split, transposed + 16B-XOR-swizzled ----------------
__global__ void prepW_k(const float* __restrict__ rW, const float* __restrict__ wW,
                        ushort* __restrict__ ws) {
    int i = blockIdx.x * blockDim.x + threadIdx.x;
    if (i >= 6 * 16384) return;
    int m = i >> 14, idx = i & 16383;
    const float* W = (m < 3) ? rW + m * 16384 : wW + (m - 3) * 16384;
    float x = W[idx];
    int k = idx >> 7, c = idx & 127;
    ushort hb = f2bf(x);
    ushort lb = f2bf(x - bf2f(hb));
    int off = ((c * 256 + 2 * k) ^ ((c & 7) << 4)) >> 1;
    ws[(size_t)m * 32768 + off] = hb;
    ws[(size_t)m * 32768 + 16384 + off] = lb;
}

// ---------------- pass 1: bin edges by dst-range into global buckets ----------------
// Block handles CHUNK contiguous edges of one graph; LDS bins -> one reservation
// atomic per bucket -> dense coalesced bucket writes. Bucket = (graph, dst/RANGE).
__global__ __launch_bounds__(256) void bucket_k(const int* __restrict__ redge,
                                                const int* __restrict__ wedge,
                                                int* __restrict__ gbcnt,
                                                int* __restrict__ bsrc,
                                                int* __restrict__ bdst) {
    __shared__ int lsrc[8][BCAP];
    __shared__ int ldst[8][BCAP];
    __shared__ int lcnt[8];
    __shared__ int gbase[8];
    const int NB = (NEDGE + CHUNK - 1) / CHUNK;
    int bid = blockIdx.x;
    int graph = bid >= NB;
    int cb = graph ? bid - NB : bid;
    const int* eg = graph ? wedge : redge;
    int e0 = cb * CHUNK;
    int nthis = min(CHUNK, NEDGE - e0);
    if (threadIdx.x < 8) lcnt[threadIdx.x] = 0;
    __syncthreads();
    for (int i = threadIdx.x; i < nthis; i += 256) {
        int s = eg[e0 + i];
        int d = eg[NEDGE + e0 + i];
        int b = d / RANGE;
        int slot = atomicAdd(&lcnt[b], 1);
        if (slot < BCAP) { lsrc[b][slot] = s; ldst[b][slot] = d; }
        else {   // statistical overflow safety net
            int gs = atomicAdd(&gbcnt[graph * 8 + b], 1);
            size_t base = ((size_t)graph * 8 + b) * BUCKET_CAP + gs;
            bsrc[base] = s; bdst[base] = d;
        }
    }
    __syncthreads();
    if (threadIdx.x < 8) {
        int c = min(lcnt[threadIdx.x], BCAP);
        lcnt[threadIdx.x] = c;
        gbase[threadIdx.x] = atomicAdd(&gbcnt[graph * 8 + threadIdx.x], c);
    }
    __syncthreads();
    #pragma unroll
    for (int b = 0; b < 8; ++b) {
        int c = lcnt[b];
        size_t base = ((size_t)graph * 8 + b) * BUCKET_CAP + gbase[b];
        for (int i = threadIdx.x; i < c; i += 256) {
            bsrc[base + i] = lsrc[b][i];
            bdst[base + i] = ldst[b][i];
        }
    }
}

// ---------------- pass 2a: histogram from buckets (L2-local atomics) ----------------
// combo = blockIdx%16 -> (range, graph); 32 blocks/combo read only their ~1MB bucket.
__global__ __launch_bounds__(256) void histb_k(const int* __restrict__ bdst,
                                               const int* __restrict__ gbcnt,
                                               int* __restrict__ cnt) {
    int combo = blockIdx.x & 15;
    int graph = combo >> 3, grp = combo & 7;
    int n = gbcnt[graph * 8 + grp];
    const int* bd = bdst + ((size_t)graph * 8 + grp) * BUCKET_CAP;
    int* c = cnt + graph * NNODE;
    for (int i = (blockIdx.x >> 4) * 256 + threadIdx.x; i < n; i += 32 * 256)
        atomicAdd(&c[bd[i]], 1);
}

// ---------------- per-graph exclusive scan (blockIdx = graph) ----------------
__global__ __launch_bounds__(1024) void scan2_k(const int* __restrict__ cnt,
                                                int* __restrict__ rp, int* __restrict__ cur) {
    const int g = blockIdx.x;
    const int* c = cnt + (size_t)g * NNODE;
    int* rpg = rp + (size_t)g * (NNODE + 1);
    int* cg = cur + (size_t)g * NNODE;
    __shared__ int wsum[16];
    __shared__ int s_carry;
    int tid = threadIdx.x, lane = tid & 63, wid = tid >> 6;
    if (tid == 0) s_carry = 0;
    __syncthreads();
    for (int base = 0; base < NNODE; base += 1024) {
        int i = base + tid;
        int v = (i < NNODE) ? c[i] : 0;
        int incl = v;
        #pragma unroll
        for (int off = 1; off < 64; off <<= 1) {
            int t = __shfl_up(incl, off, 64);
            if (lane >= off) incl += t;
        }
        if (lane == 63) wsum[wid] = incl;
        __syncthreads();
        int carry = s_carry;
        if (wid == 0 && lane < 16) {
            int wv = wsum[lane];
            #pragma unroll
            for (int off = 1; off < 16; off <<= 1) {
                int t = __shfl_up(wv, off, 64);
                if (lane >= off) wv += t;
            }
            wsum[lane] = wv;
        }
        __syncthreads();
        int waveoff = (wid == 0) ? 0 : wsum[wid - 1];
        int excl = carry + waveoff + incl - v;
        if (i < NNODE) { rpg[i] = excl; cg[i] = excl; }
        __syncthreads();
        if (tid == 0) s_carry = carry + wsum[15];
        __syncthreads();
    }
    if (threadIdx.x == 0) rpg[NNODE] = s_carry;
}

// ---------------- pass 2b: CSR fill from buckets ----------------
// Streaming read is only the combo's ~1MB bucket -> csr write window (~500KB) and
// cursor slice (35KB) stay L2-resident -> full-line evictions.
__global__ __launch_bounds__(256) void fillb_k(const int* __restrict__ bsrc,
                                               const int* __restrict__ bdst,
                                               const int* __restrict__ gbcnt,
                                               int* __restrict__ cur,
                                               int* __restrict__ csr) {
    int combo = blockIdx.x & 15;
    int graph = combo >> 3, grp = combo & 7;
    int n = gbcnt[graph * 8 + grp];
    size_t base = ((size_t)graph * 8 + grp) * BUCKET_CAP;
    int* cg = cur + graph * NNODE;
    int* og = csr + graph * NEDGE;
    for (int i = (blockIdx.x >> 4) * 256 + threadIdx.x; i < n; i += 32 * 256) {
        int d = bdst[base + i];
        int s = bsrc[base + i];
        og[atomicAdd(&cg[d], 1)] = s;
    }
}

// ---------------- cvt both graphs: fcR = bf16(rcj ⊙ feat), fcW = bf16(wcj ⊙ feat) ---------
__global__ __launch_bounds__(256) void cvt2_k(const float* __restrict__ stu,
                                              const float* __restrict__ exer,
                                              const float* __restrict__ rcj,
                                              const float* __restrict__ wcj,
                                              ushort* __restrict__ fcR,
                                              ushort* __restrict__ fcW) {
    const int total = NNODE * 32;
    for (int i = blockIdx.x * blockDim.x + threadIdx.x; i < total;
         i += gridDim.x * blockDim.x) {
        int node = i >> 5;
        int q = i & 31;
        const float* src = (node < S_NUM) ? stu + (size_t)node * KDIM
                                          : exer + (size_t)(node - S_NUM) * KDIM;
        float4 v = ((const float4*)src)[q];
        float cr = rcj[node], cw = wcj[node];
        uint2 oR, oW;
        oR.x = (uint32_t)f2bf(v.x * cr) | ((uint32_t)f2bf(v.y * cr) << 16);
        oR.y = (uint32_t)f2bf(v.z * cr) | ((uint32_t)f2bf(v.w * cr) << 16);
        oW.x = (uint32_t)f2bf(v.x * cw) | ((uint32_t)f2bf(v.y * cw) << 16);
        oW.y = (uint32_t)f2bf(v.z * cw) | ((uint32_t)f2bf(v.w * cw) << 16);
        *(uint2*)(fcR + (size_t)node * KDIM + q * 4) = oR;
        *(uint2*)(fcW + (size_t)node * KDIM + q * 4) = oW;
    }
}

// ---------------- fused aggregation, both graphs ----------------
// One wave per node. Lane L: row-group L>>4 (4 rows per load step), uint4 = 8 dims.
// One vmem instr gathers 4 rows (1KB); unroll 2 -> 8 rows in flight.
// Final: shfl_xor(16/32) reduce across row-groups; lanes 0-15 write the row.
__global__ __launch_bounds__(256) void agg2_k(const uint4* __restrict__ fcR,
                                              const uint4* __restrict__ fcW,
                                              const int* __restrict__ rp,
                                              const int* __restrict__ csr,
                                              uint4* __restrict__ outR,
                                              uint4* __restrict__ outW) {
    int gn = (blockIdx.x * blockDim.x + threadIdx.x) >> 6;
    if (gn >= 2 * NNODE) return;
    int graph = gn >= NNODE;
    int n = graph ? gn - NNODE : gn;
    const uint4* fc = graph ? fcW : fcR;
    const int* rpg = rp + graph * (NNODE + 1);
    const int* cs = csr + graph * NEDGE;
    uint4* outp = graph ? outW : outR;

    int lane = threadIdx.x & 63;
    int rowgrp = lane >> 4, c16 = lane & 15;
    int beg = rpg[n], end = rpg[n + 1];
    float acc[8];
    #pragma unroll
    for (int j = 0; j < 8; ++j) acc[j] = 0.f;

    for (int e = beg; e < end; e += 8) {
        int r0 = e + rowgrp, r1 = e + 4 + rowgrp;
        uint4 u0 = {0, 0, 0, 0}, u1 = {0, 0, 0, 0};
        if (r0 < end) u0 = fc[(size_t)cs[r0] * 16 + c16];
        if (r1 < end) u1 = fc[(size_t)cs[r1] * 16 + c16];
        acc[0] += lo2f(u0.x) + lo2f(u1.x);
        acc[1] += hi2f(u0.x) + hi2f(u1.x);
        acc[2] += lo2f(u0.y) + lo2f(u1.y);
        acc[3] += hi2f(u0.y) + hi2f(u1.y);
        acc[4] += lo2f(u0.z) + lo2f(u1.z);
        acc[5] += hi2f(u0.z) + hi2f(u1.z);
        acc[6] += lo2f(u0.w) + lo2f(u1.w);
        acc[7] += hi2f(u0.w) + hi2f(u1.w);
    }
    #pragma unroll
    for (int j = 0; j < 8; ++j) {
        acc[j] += __shfl_xor(acc[j], 16, 64);
        acc[j] += __shfl_xor(acc[j], 32, 64);
    }
    if (rowgrp == 0) {
        uint4 o;
        o.x = (uint32_t)f2bf(acc[0]) | ((uint32_t)f2bf(acc[1]) << 16);
        o.y = (uint32_t)f2bf(acc[2]) | ((uint32_t)f2bf(acc[3]) << 16);
        o.z = (uint32_t)f2bf(acc[4]) | ((uint32_t)f2bf(acc[5]) << 16);
        o.w = (uint32_t)f2bf(acc[6]) | ((uint32_t)f2bf(acc[7]) << 16);
        outp[(size_t)n * 16 + c16] = o;
    }
}

// ---------------- fused GEMM, both graphs: out = bf16( scal ⊙ (A @ W) ) ----------------
__global__ __launch_bounds__(256) void gemm2_k(const ushort* __restrict__ AR,
                                               const ushort* __restrict__ AW,
                                               const ushort* __restrict__ wsR,
                                               const ushort* __restrict__ wsW,
                                               const float* __restrict__ rci,
                                               const float* __restrict__ rcj,
                                               const float* __restrict__ wci,
                                               const float* __restrict__ wcj,
                                               ushort* __restrict__ outR,
                                               ushort* __restrict__ outW,
                                               int mode) {
    const int halfBlocks = (NNODE + 63) / 64;
    int graph = blockIdx.x >= halfBlocks;
    int bb = graph ? blockIdx.x - halfBlocks : blockIdx.x;
    const ushort* A = graph ? AW : AR;
    const ushort* wsm = graph ? wsW : wsR;
    const float* ci = graph ? wci : rci;
    const float* cj = graph ? wcj : rcj;
    ushort* outB = graph ? outW : outR;

    __shared__ ushort wt[32768];   // 64 KB: hi + lo plane, pre-swizzled
    {
        const uint4* g = (const uint4*)wsm;
        uint4* l = (uint4*)wt;
        for (int i = threadIdx.x; i < 4096; i += 256) l[i] = g[i];
    }
    __syncthreads();

    int wid = threadIdx.x >> 6, lane = threadIdx.x & 63;
    int rbase = bb * 64 + wid * 16;
    if (rbase >= NNODE) return;

    int arow = rbase + (lane & 15);
    bool rok = arow < NNODE;
    int q = lane >> 4;
    short8 z8 = {0, 0, 0, 0, 0, 0, 0, 0};
    const short8* ar = (const short8*)(A + (size_t)arow * KDIM);
    short8 afr[4];
    #pragma unroll
    for (int kb = 0; kb < 4; ++kb)
        afr[kb] = rok ? ar[kb * 4 + q] : z8;

    int rq = q * 4;
    float scal[4];
    #pragma unroll
    for (int b = 0; b < 4; ++b) {
        int r = rbase + rq + b;
        scal[b] = (r < NNODE) ? (mode ? ci[r] * cj[r] : ci[r]) : 0.f;
    }
    #pragma unroll
    for (int cb = 0; cb < 8; ++cb) {
        f32x4 acc = {0.f, 0.f, 0.f, 0.f};
        int c = cb * 16 + (lane & 15);
        #pragma unroll
        for (int kb = 0; kb < 4; ++kb) {
            int byte = (c * 256 + 2 * (kb * 32 + q * 8)) ^ ((c & 7) << 4);
            short8 bHi = *(const short8*)((const char*)wt + byte);
            short8 bLo = *(const short8*)((const char*)wt + 32768 + byte);
            acc = __builtin_amdgcn_mfma_f32_16x16x32_bf16(afr[kb], bHi, acc, 0, 0, 0);
            acc = __builtin_amdgcn_mfma_f32_16x16x32_bf16(afr[kb], bLo, acc, 0, 0, 0);
        }
        #pragma unroll
        for (int b = 0; b < 4; ++b) {
            int r = rbase + rq + b;
            if (r < NNODE)
                outB[(size_t)r * KDIM + c] = f2bf(acc[b] * scal[b]);
        }
    }
}

// ---------------- output assembly (w1/w2 bf16 -> f32 out) ----------------
__global__ void out_k(const ushort* __restrict__ w1, const ushort* __restrict__ w2,
                      const float* __restrict__ disc, const float* __restrict__ kn,
                      const int* __restrict__ sid, const int* __restrict__ eid,
                      float* __restrict__ out) {
    const int total = 2 * BATCH * KDIM + BATCH + KDIM * KDIM;
    for (int i = blockIdx.x * blockDim.x + threadIdx.x; i < total;
         i += gridDim.x * blockDim.x) {
        if (i < BATCH * KDIM) {
            int b = i >> 7, c = i & 127;
            size_t n = (size_t)sid[b];
            out[i] = bf2f(w1[n * KDIM + c]) + bf2f(w2[n * KDIM + c]);
        } else if (i < 2 * BATCH * KDIM) {
            int j = i - BATCH * KDIM;
            int b = j >> 7, c = j & 127;
            size_t n = (size_t)(S_NUM + eid[b]);
            out[i] = bf2f(w1[n * KDIM + c]) + bf2f(w2[n * KDIM + c]);
        } else if (i < 2 * BATCH * KDIM + BATCH) {
            out[i] = disc[eid[i - 2 * BATCH * KDIM]];
        } else {
            out[i] = kn[i - (2 * BATCH * KDIM + BATCH)];
        }
    }
}

static inline size_t align_up(size_t x) { return (x + 255) & ~(size_t)255; }

extern "C" void kernel_launch(void* const* d_in, const int* in_sizes, int n_in,
                              void* d_out, int out_size, void* d_ws, size_t ws_size,
                              hipStream_t stream) {
    const float* stu  = (const float*)d_in[0];
    const float* exer = (const float*)d_in[1];
    const float* kn   = (const float*)d_in[2];
    const float* disc = (const float*)d_in[3];
    const float* rW   = (const float*)d_in[4];
    const float* wW   = (const float*)d_in[5];
    const float* rci  = (const float*)d_in[6];
    const float* rcj  = (const float*)d_in[7];
    const float* wci  = (const float*)d_in[8];
    const float* wcj  = (const float*)d_in[9];
    const int* redge   = (const int*)d_in[10];
    const int* wedge   = (const int*)d_in[11];
    const int* sid     = (const int*)d_in[12];
    const int* eid     = (const int*)d_in[13];
    float* out         = (float*)d_out;

    char* p = (char*)d_ws;
    const size_t fB16 = align_up((size_t)NNODE * KDIM * 2);   // 17.92 MB
    ushort* fcR = (ushort*)p; p += fB16;   // also w1; also aliases buckets pre-cvt2
    ushort* fcW = (ushort*)p; p += fB16;   // also w2
    ushort* pR  = (ushort*)p; p += fB16;
    ushort* pW  = (ushort*)p; p += fB16;
    ushort* ws  = (ushort*)p; p += align_up((size_t)6 * 32768 * 2);   // 384 KB
    int* cnt = (int*)p; p += align_up((size_t)(2 * NNODE + 16) * 4);
    int* rp  = (int*)p; p += align_up((size_t)2 * (NNODE + 1) * 4);
    int* cur = (int*)p; p += align_up((size_t)2 * NNODE * 4);
    int* csr = (int*)p; p += align_up((size_t)2 * NEDGE * 4);
    int* gbcnt = cnt + 2 * NNODE;
    // buckets alias fcR (16 buckets x 131072 x 4B x 2 arrays = 16.8 MB < 17.92 MB);
    // consumed by fillb_k before cvt2_k writes fcR.
    int* bsrc = (int*)fcR;
    int* bdst = bsrc + 16 * BUCKET_CAP;

    const int gemmBlocks2 = 2 * ((NNODE + 63) / 64);
    const int aggBlocks2 = (2 * NNODE * 64) / 256;
    const int NB = (NEDGE + CHUNK - 1) / CHUNK;

    // ---- shared prep: W split + both CSRs (bucketed build) ----
    prepW_k<<<(6 * 16384 + 255) / 256, 256, 0, stream>>>(rW, wW, ws);
    zero_k<<<(2 * NNODE + 16 + 255) / 256, 256, 0, stream>>>(cnt, 2 * NNODE + 16);
    bucket_k<<<2 * NB, 256, 0, stream>>>(redge, wedge, gbcnt, bsrc, bdst);
    histb_k<<<512, 256, 0, stream>>>(bdst, gbcnt, cnt);
    scan2_k<<<2, 1024, 0, stream>>>(cnt, rp, cur);
    fillb_k<<<512, 256, 0, stream>>>(bsrc, bdst, gbcnt, cur, csr);
    cvt2_k<<<2048, 256, 0, stream>>>(stu, exer, rcj, wcj, fcR, fcW);

    // ---- 3 layers, both graphs fused per dispatch ----
    agg2_k<<<aggBlocks2, 256, 0, stream>>>((const uint4*)fcR, (const uint4*)fcW,
                                           rp, csr, (uint4*)pR, (uint4*)pW);
    gemm2_k<<<gemmBlocks2, 256, 0, stream>>>(pR, pW, ws + 0 * 32768, ws + 3 * 32768,
                                             rci, rcj, wci, wcj, fcR, fcW, 1);
    agg2_k<<<aggBlocks2, 256, 0, stream>>>((const uint4*)fcR, (const uint4*)fcW,
                                           rp, csr, (uint4*)pR, (uint4*)pW);
    gemm2_k<<<gemmBlocks2, 256, 0, stream>>>(pR, pW, ws + 1 * 32768, ws + 4 * 32768,
                                             rci, rcj, wci, wcj, fcR, fcW, 1);
    agg2_k<<<aggBlocks2, 256, 0, stream>>>((const uint4*)fcR, (const uint4*)fcW,
                                           rp, csr, (uint4*)pR, (uint4*)pW);
    gemm2_k<<<gemmBlocks2, 256, 0, stream>>>(pR, pW, ws + 2 * 32768, ws + 5 * 32768,
                                             rci, rcj, wci, wcj, fcR, fcW, 0);

    out_k<<<2048, 256, 0, stream>>>(fcR, fcW, disc, kn, sid, eid, out);
}

// Round 7
// 424.539 us; speedup vs baseline: 2.8429x; 1.4437x over previous
//
#include <hip/hip_runtime.h>
#include <hip/hip_bf16.h>
#include <stdint.h>

#define S_NUM 50000
#define E_NUM 20000
#define NNODE 70000
#define KDIM 128
#define BATCH 8192
#define NEDGE 1000000

#define NRANGE 128            // dst-ranges per graph
#define RSZ 547               // ceil(NNODE / NRANGE); 128*547 = 70016
#define BUCKET_CAP 8448       // per-bucket capacity (mean 7813, sigma 88 -> 7.2 sigma)
#define CHUNK 8192            // edges per bucket_k block
#define BINCAP 120            // LDS bin capacity (mean 64, sigma 8 -> 7 sigma)

typedef __attribute__((ext_vector_type(8))) short short8;
typedef __attribute__((ext_vector_type(4))) float f32x4;

__device__ __forceinline__ float bf2f(ushort u) {
    union { uint32_t i; float f; } v; v.i = ((uint32_t)u) << 16; return v.f;
}
__device__ __forceinline__ ushort f2bf(float f) {
    union { uint32_t i; float f; } v; v.f = f;
    uint32_t r = v.i + 0x7fffu + ((v.i >> 16) & 1u);
    return (ushort)(r >> 16);
}
__device__ __forceinline__ float hi2f(uint32_t u) {
    union { uint32_t i; float f; } v; v.i = u & 0xffff0000u; return v.f;
}
__device__ __forceinline__ float lo2f(uint32_t u) {
    union { uint32_t i; float f; } v; v.i = u << 16; return v.f;
}

__global__ void zero_k(int* __restrict__ p, int n) {
    for (int i = blockIdx.x * blockDim.x + threadIdx.x; i < n; i += gridDim.x * blockDim.x)
        p[i] = 0;
}

// ---------------- W prep: bf16 hi/lo split, transposed + 16B-XOR-swizzled ----------------
__global__ void prepW_k(const float* __restrict__ rW, const float* __restrict__ wW,
                        ushort* __restrict__ ws) {
    int i = blockIdx.x * blockDim.x + threadIdx.x;
    if (i >= 6 * 16384) return;
    int m = i >> 14, idx = i & 16383;
    const float* W = (m < 3) ? rW + m * 16384 : wW + (m - 3) * 16384;
    float x = W[idx];
    int k = idx >> 7, c = idx & 127;
    ushort hb = f2bf(x);
    ushort lb = f2bf(x - bf2f(hb));
    int off = ((c * 256 + 2 * k) ^ ((c & 7) << 4)) >> 1;
    ws[(size_t)m * 32768 + off] = hb;
    ws[(size_t)m * 32768 + 16384 + off] = lb;
}

// ---------------- pass 1: bin edges by dst-range, packed (local_dst<<17 | src) -------------
// Block = CHUNK contiguous edges of one graph; LDS bins -> one reservation atomic per
// bin -> ~256B dense runs into global buckets.
__global__ __launch_bounds__(256) void bucket_k(const int* __restrict__ redge,
                                                const int* __restrict__ wedge,
                                                int* __restrict__ gbcnt,
                                                uint32_t* __restrict__ bpk) {
    __shared__ uint32_t lpk[NRANGE][BINCAP];
    __shared__ int lcnt[NRANGE];
    __shared__ int gbase[NRANGE];
    const int NB = (NEDGE + CHUNK - 1) / CHUNK;
    int bid = blockIdx.x;
    int graph = bid >= NB;
    int cb = graph ? bid - NB : bid;
    const int* eg = graph ? wedge : redge;
    int e0 = cb * CHUNK;
    int nthis = min(CHUNK, NEDGE - e0);
    for (int i = threadIdx.x; i < NRANGE; i += 256) lcnt[i] = 0;
    __syncthreads();
    for (int i = threadIdx.x; i < nthis; i += 256) {
        int s = eg[e0 + i];
        int d = eg[NEDGE + e0 + i];
        int b = d / RSZ;
        uint32_t p = ((uint32_t)(d - b * RSZ) << 17) | (uint32_t)s;
        int slot = atomicAdd(&lcnt[b], 1);
        if (slot < BINCAP) lpk[b][slot] = p;
        else {   // statistical overflow safety net
            int gs = atomicAdd(&gbcnt[graph * NRANGE + b], 1);
            if (gs < BUCKET_CAP)
                bpk[(size_t)(graph * NRANGE + b) * BUCKET_CAP + gs] = p;
        }
    }
    __syncthreads();
    for (int b = threadIdx.x; b < NRANGE; b += 256) {
        int c = min(lcnt[b], BINCAP);
        lcnt[b] = c;
        gbase[b] = atomicAdd(&gbcnt[graph * NRANGE + b], c);
    }
    __syncthreads();
    for (int b = 0; b < NRANGE; ++b) {
        int c = lcnt[b];
        size_t base = (size_t)(graph * NRANGE + b) * BUCKET_CAP + gbase[b];
        for (int i = threadIdx.x; i < c; i += 256)
            if (gbase[b] + i < BUCKET_CAP) bpk[base + i] = lpk[b][i];
    }
}

// ---------------- pass 2: per-combo CSR slice built in LDS, written densely ----------------
// One block per (range, graph). Local histogram + scan + LDS scatter; all global
// writes (rp slice, csr slice) are dense full-line stores -> no write amplification.
__global__ __launch_bounds__(256) void build_k(const uint32_t* __restrict__ bpk,
                                               const int* __restrict__ gbcnt,
                                               int* __restrict__ rp,
                                               int* __restrict__ csr) {
    __shared__ int lcnt[RSZ + 1];
    __shared__ int lexcl[RSZ];
    __shared__ int lcur[RSZ];
    __shared__ int slice[BUCKET_CAP];
    __shared__ int wsum[4];
    __shared__ int s_base, s_carry;
    int combo = blockIdx.x;                 // 0..255
    int graph = combo >> 7, grp = combo & (NRANGE - 1);
    int lo = grp * RSZ;
    int rsize = min(RSZ, NNODE - lo);
    int n = min(gbcnt[combo], BUCKET_CAP);
    const uint32_t* bp = bpk + (size_t)combo * BUCKET_CAP;
    int* rpg = rp + graph * (NNODE + 1);
    int* og = csr + graph * NEDGE;
    int tid = threadIdx.x, lane = tid & 63, wid = tid >> 6;

    // global base = sum of earlier buckets of this graph (staged via lcnt)
    if (tid < NRANGE) lcnt[tid] = min(gbcnt[graph * NRANGE + tid], BUCKET_CAP);
    __syncthreads();
    if (tid == 0) {
        int b = 0;
        for (int i = 0; i < grp; ++i) b += lcnt[i];
        s_base = b;
        s_carry = 0;
    }
    __syncthreads();
    for (int i = tid; i < rsize; i += 256) lcnt[i] = 0;
    __syncthreads();
    // local histogram
    for (int i = tid; i < n; i += 256)
        atomicAdd(&lcnt[bp[i] >> 17], 1);
    __syncthreads();
    // exclusive scan over lcnt[0..rsize)
    for (int base = 0; base < rsize; base += 256) {
        int i = base + tid;
        int v = (i < rsize) ? lcnt[i] : 0;
        int incl = v;
        #pragma unroll
        for (int off = 1; off < 64; off <<= 1) {
            int t = __shfl_up(incl, off, 64);
            if (lane >= off) incl += t;
        }
        if (lane == 63) wsum[wid] = incl;
        __syncthreads();
        int carry = s_carry;
        if (wid == 0 && lane < 4) {
            int wv = wsum[lane];
            #pragma unroll
            for (int off = 1; off < 4; off <<= 1) {
                int t = __shfl_up(wv, off, 64);
                if (lane >= off) wv += t;
            }
            wsum[lane] = wv;
        }
        __syncthreads();
        int waveoff = (wid == 0) ? 0 : wsum[wid - 1];
        int excl = carry + waveoff + incl - v;
        if (i < rsize) { lexcl[i] = excl; lcur[i] = excl; }
        __syncthreads();
        if (tid == 0) s_carry = carry + wsum[3];
        __syncthreads();
    }
    int gbas = s_base;
    // rp slice (dense)
    for (int i = tid; i < rsize; i += 256)
        rpg[lo + i] = gbas + lexcl[i];
    if (grp == NRANGE - 1 && tid == 0) rpg[NNODE] = gbas + n;
    // LDS scatter (counting-sort placement)
    for (int i = tid; i < n; i += 256) {
        uint32_t p = bp[i];
        int slot = atomicAdd(&lcur[p >> 17], 1);
        slice[slot] = (int)(p & 0x1FFFFu);
    }
    __syncthreads();
    // csr slice (dense full-line writes)
    for (int i = tid; i < n; i += 256)
        og[gbas + i] = slice[i];
}

// ---------------- cvt both graphs: fcR = bf16(rcj ⊙ feat), fcW = bf16(wcj ⊙ feat) ---------
__global__ __launch_bounds__(256) void cvt2_k(const float* __restrict__ stu,
                                              const float* __restrict__ exer,
                                              const float* __restrict__ rcj,
                                              const float* __restrict__ wcj,
                                              ushort* __restrict__ fcR,
                                              ushort* __restrict__ fcW) {
    const int total = NNODE * 32;
    for (int i = blockIdx.x * blockDim.x + threadIdx.x; i < total;
         i += gridDim.x * blockDim.x) {
        int node = i >> 5;
        int q = i & 31;
        const float* src = (node < S_NUM) ? stu + (size_t)node * KDIM
                                          : exer + (size_t)(node - S_NUM) * KDIM;
        float4 v = ((const float4*)src)[q];
        float cr = rcj[node], cw = wcj[node];
        uint2 oR, oW;
        oR.x = (uint32_t)f2bf(v.x * cr) | ((uint32_t)f2bf(v.y * cr) << 16);
        oR.y = (uint32_t)f2bf(v.z * cr) | ((uint32_t)f2bf(v.w * cr) << 16);
        oW.x = (uint32_t)f2bf(v.x * cw) | ((uint32_t)f2bf(v.y * cw) << 16);
        oW.y = (uint32_t)f2bf(v.z * cw) | ((uint32_t)f2bf(v.w * cw) << 16);
        *(uint2*)(fcR + (size_t)node * KDIM + q * 4) = oR;
        *(uint2*)(fcW + (size_t)node * KDIM + q * 4) = oW;
    }
}

// ---------------- fused aggregation, both graphs ----------------
__global__ __launch_bounds__(256) void agg2_k(const uint4* __restrict__ fcR,
                                              const uint4* __restrict__ fcW,
                                              const int* __restrict__ rp,
                                              const int* __restrict__ csr,
                                              uint4* __restrict__ outR,
                                              uint4* __restrict__ outW) {
    int gn = (blockIdx.x * blockDim.x + threadIdx.x) >> 6;
    if (gn >= 2 * NNODE) return;
    int graph = gn >= NNODE;
    int n = graph ? gn - NNODE : gn;
    const uint4* fc = graph ? fcW : fcR;
    const int* rpg = rp + graph * (NNODE + 1);
    const int* cs = csr + graph * NEDGE;
    uint4* outp = graph ? outW : outR;

    int lane = threadIdx.x & 63;
    int rowgrp = lane >> 4, c16 = lane & 15;
    int beg = rpg[n], end = rpg[n + 1];
    float acc[8];
    #pragma unroll
    for (int j = 0; j < 8; ++j) acc[j] = 0.f;

    for (int e = beg; e < end; e += 8) {
        int r0 = e + rowgrp, r1 = e + 4 + rowgrp;
        uint4 u0 = {0, 0, 0, 0}, u1 = {0, 0, 0, 0};
        if (r0 < end) u0 = fc[(size_t)cs[r0] * 16 + c16];
        if (r1 < end) u1 = fc[(size_t)cs[r1] * 16 + c16];
        acc[0] += lo2f(u0.x) + lo2f(u1.x);
        acc[1] += hi2f(u0.x) + hi2f(u1.x);
        acc[2] += lo2f(u0.y) + lo2f(u1.y);
        acc[3] += hi2f(u0.y) + hi2f(u1.y);
        acc[4] += lo2f(u0.z) + lo2f(u1.z);
        acc[5] += hi2f(u0.z) + hi2f(u1.z);
        acc[6] += lo2f(u0.w) + lo2f(u1.w);
        acc[7] += hi2f(u0.w) + hi2f(u1.w);
    }
    #pragma unroll
    for (int j = 0; j < 8; ++j) {
        acc[j] += __shfl_xor(acc[j], 16, 64);
        acc[j] += __shfl_xor(acc[j], 32, 64);
    }
    if (rowgrp == 0) {
        uint4 o;
        o.x = (uint32_t)f2bf(acc[0]) | ((uint32_t)f2bf(acc[1]) << 16);
        o.y = (uint32_t)f2bf(acc[2]) | ((uint32_t)f2bf(acc[3]) << 16);
        o.z = (uint32_t)f2bf(acc[4]) | ((uint32_t)f2bf(acc[5]) << 16);
        o.w = (uint32_t)f2bf(acc[6]) | ((uint32_t)f2bf(acc[7]) << 16);
        outp[(size_t)n * 16 + c16] = o;
    }
}

// ---------------- fused GEMM, both graphs: out = bf16( scal ⊙ (A @ W) ) ----------------
__global__ __launch_bounds__(256) void gemm2_k(const ushort* __restrict__ AR,
                                               const ushort* __restrict__ AW,
                                               const ushort* __restrict__ wsR,
                                               const ushort* __restrict__ wsW,
                                               const float* __restrict__ rci,
                                               const float* __restrict__ rcj,
                                               const float* __restrict__ wci,
                                               const float* __restrict__ wcj,
                                               ushort* __restrict__ outR,
                                               ushort* __restrict__ outW,
                                               int mode) {
    const int halfBlocks = (NNODE + 63) / 64;
    int graph = blockIdx.x >= halfBlocks;
    int bb = graph ? blockIdx.x - halfBlocks : blockIdx.x;
    const ushort* A = graph ? AW : AR;
    const ushort* wsm = graph ? wsW : wsR;
    const float* ci = graph ? wci : rci;
    const float* cj = graph ? wcj : rcj;
    ushort* outB = graph ? outW : outR;

    __shared__ ushort wt[32768];   // 64 KB: hi + lo plane, pre-swizzled
    {
        const uint4* g = (const uint4*)wsm;
        uint4* l = (uint4*)wt;
        for (int i = threadIdx.x; i < 4096; i += 256) l[i] = g[i];
    }
    __syncthreads();

    int wid = threadIdx.x >> 6, lane = threadIdx.x & 63;
    int rbase = bb * 64 + wid * 16;
    if (rbase >= NNODE) return;

    int arow = rbase + (lane & 15);
    bool rok = arow < NNODE;
    int q = lane >> 4;
    short8 z8 = {0, 0, 0, 0, 0, 0, 0, 0};
    const short8* ar = (const short8*)(A + (size_t)arow * KDIM);
    short8 afr[4];
    #pragma unroll
    for (int kb = 0; kb < 4; ++kb)
        afr[kb] = rok ? ar[kb * 4 + q] : z8;

    int rq = q * 4;
    float scal[4];
    #pragma unroll
    for (int b = 0; b < 4; ++b) {
        int r = rbase + rq + b;
        scal[b] = (r < NNODE) ? (mode ? ci[r] * cj[r] : ci[r]) : 0.f;
    }
    #pragma unroll
    for (int cb = 0; cb < 8; ++cb) {
        f32x4 acc = {0.f, 0.f, 0.f, 0.f};
        int c = cb * 16 + (lane & 15);
        #pragma unroll
        for (int kb = 0; kb < 4; ++kb) {
            int byte = (c * 256 + 2 * (kb * 32 + q * 8)) ^ ((c & 7) << 4);
            short8 bHi = *(const short8*)((const char*)wt + byte);
            short8 bLo = *(const short8*)((const char*)wt + 32768 + byte);
            acc = __builtin_amdgcn_mfma_f32_16x16x32_bf16(afr[kb], bHi, acc, 0, 0, 0);
            acc = __builtin_amdgcn_mfma_f32_16x16x32_bf16(afr[kb], bLo, acc, 0, 0, 0);
        }
        #pragma unroll
        for (int b = 0; b < 4; ++b) {
            int r = rbase + rq + b;
            if (r < NNODE)
                outB[(size_t)r * KDIM + c] = f2bf(acc[b] * scal[b]);
        }
    }
}

// ---------------- output assembly (w1/w2 bf16 -> f32 out) ----------------
__global__ void out_k(const ushort* __restrict__ w1, const ushort* __restrict__ w2,
                      const float* __restrict__ disc, const float* __restrict__ kn,
                      const int* __restrict__ sid, const int* __restrict__ eid,
                      float* __restrict__ out) {
    const int total = 2 * BATCH * KDIM + BATCH + KDIM * KDIM;
    for (int i = blockIdx.x * blockDim.x + threadIdx.x; i < total;
         i += gridDim.x * blockDim.x) {
        if (i < BATCH * KDIM) {
            int b = i >> 7, c = i & 127;
            size_t n = (size_t)sid[b];
            out[i] = bf2f(w1[n * KDIM + c]) + bf2f(w2[n * KDIM + c]);
        } else if (i < 2 * BATCH * KDIM) {
            int j = i - BATCH * KDIM;
            int b = j >> 7, c = j & 127;
            size_t n = (size_t)(S_NUM + eid[b]);
            out[i] = bf2f(w1[n * KDIM + c]) + bf2f(w2[n * KDIM + c]);
        } else if (i < 2 * BATCH * KDIM + BATCH) {
            out[i] = disc[eid[i - 2 * BATCH * KDIM]];
        } else {
            out[i] = kn[i - (2 * BATCH * KDIM + BATCH)];
        }
    }
}

static inline size_t align_up(size_t x) { return (x + 255) & ~(size_t)255; }

extern "C" void kernel_launch(void* const* d_in, const int* in_sizes, int n_in,
                              void* d_out, int out_size, void* d_ws, size_t ws_size,
                              hipStream_t stream) {
    const float* stu  = (const float*)d_in[0];
    const float* exer = (const float*)d_in[1];
    const float* kn   = (const float*)d_in[2];
    const float* disc = (const float*)d_in[3];
    const float* rW   = (const float*)d_in[4];
    const float* wW   = (const float*)d_in[5];
    const float* rci  = (const float*)d_in[6];
    const float* rcj  = (const float*)d_in[7];
    const float* wci  = (const float*)d_in[8];
    const float* wcj  = (const float*)d_in[9];
    const int* redge   = (const int*)d_in[10];
    const int* wedge   = (const int*)d_in[11];
    const int* sid     = (const int*)d_in[12];
    const int* eid     = (const int*)d_in[13];
    float* out         = (float*)d_out;

    char* p = (char*)d_ws;
    const size_t fB16 = align_up((size_t)NNODE * KDIM * 2);   // 17.92 MB
    ushort* fcR = (ushort*)p; p += fB16;   // also w1; aliases buckets pre-cvt2
    ushort* fcW = (ushort*)p; p += fB16;   // also w2
    ushort* pR  = (ushort*)p; p += fB16;
    ushort* pW  = (ushort*)p; p += fB16;
    ushort* ws  = (ushort*)p; p += align_up((size_t)6 * 32768 * 2);   // 384 KB
    int* gbcnt = (int*)p; p += align_up((size_t)256 * 4);
    int* rp  = (int*)p; p += align_up((size_t)2 * (NNODE + 1) * 4);
    int* csr = (int*)p; p += align_up((size_t)2 * NEDGE * 4);
    // buckets alias fcR (256 x 8448 x 4B = 8.65 MB < 17.92 MB); consumed by
    // build_k before cvt2_k writes fcR.
    uint32_t* bpk = (uint32_t*)fcR;

    const int gemmBlocks2 = 2 * ((NNODE + 63) / 64);
    const int aggBlocks2 = (2 * NNODE * 64) / 256;
    const int NB = (NEDGE + CHUNK - 1) / CHUNK;

    // ---- shared prep: W split + both CSRs (bucketed, LDS-sorted build) ----
    prepW_k<<<(6 * 16384 + 255) / 256, 256, 0, stream>>>(rW, wW, ws);
    zero_k<<<1, 256, 0, stream>>>(gbcnt, 256);
    bucket_k<<<2 * NB, 256, 0, stream>>>(redge, wedge, gbcnt, bpk);
    build_k<<<256, 256, 0, stream>>>(bpk, gbcnt, rp, csr);
    cvt2_k<<<2048, 256, 0, stream>>>(stu, exer, rcj, wcj, fcR, fcW);

    // ---- 3 layers, both graphs fused per dispatch ----
    agg2_k<<<aggBlocks2, 256, 0, stream>>>((const uint4*)fcR, (const uint4*)fcW,
                                           rp, csr, (uint4*)pR, (uint4*)pW);
    gemm2_k<<<gemmBlocks2, 256, 0, stream>>>(pR, pW, ws + 0 * 32768, ws + 3 * 32768,
                                             rci, rcj, wci, wcj, fcR, fcW, 1);
    agg2_k<<<aggBlocks2, 256, 0, stream>>>((const uint4*)fcR, (const uint4*)fcW,
                                           rp, csr, (uint4*)pR, (uint4*)pW);
    gemm2_k<<<gemmBlocks2, 256, 0, stream>>>(pR, pW, ws + 1 * 32768, ws + 4 * 32768,
                                             rci, rcj, wci, wcj, fcR, fcW, 1);
    agg2_k<<<aggBlocks2, 256, 0, stream>>>((const uint4*)fcR, (const uint4*)fcW,
                                           rp, csr, (uint4*)pR, (uint4*)pW);
    gemm2_k<<<gemmBlocks2, 256, 0, stream>>>(pR, pW, ws + 2 * 32768, ws + 5 * 32768,
                                             rci, rcj, wci, wcj, fcR, fcW, 0);

    out_k<<<2048, 256, 0, stream>>>(fcR, fcW, disc, kn, sid, eid, out);
}

// Round 8
// 414.471 us; speedup vs baseline: 2.9120x; 1.0243x over previous
//
#include <hip/hip_runtime.h>
#include <hip/hip_bf16.h>
#include <stdint.h>

#define S_NUM 50000
#define E_NUM 20000
#define NNODE 70000
#define KDIM 128
#define BATCH 8192
#define NEDGE 1000000

#define NRANGE 128            // dst-ranges per graph
#define RSZ 547               // ceil(NNODE / NRANGE); 128*547 = 70016
#define BUCKET_CAP 8448       // per-bucket capacity (mean 7813, sigma 88)
#define CHUNK 8192            // edges per bucket_k block
#define BINCAP 120            // LDS bin capacity
#define GR 256                // gemm rows per block

typedef __attribute__((ext_vector_type(8))) short short8;
typedef __attribute__((ext_vector_type(4))) float f32x4;

__device__ __forceinline__ float bf2f(ushort u) {
    union { uint32_t i; float f; } v; v.i = ((uint32_t)u) << 16; return v.f;
}
__device__ __forceinline__ ushort f2bf(float f) {
    union { uint32_t i; float f; } v; v.f = f;
    uint32_t r = v.i + 0x7fffu + ((v.i >> 16) & 1u);
    return (ushort)(r >> 16);
}
__device__ __forceinline__ float hi2f(uint32_t u) {
    union { uint32_t i; float f; } v; v.i = u & 0xffff0000u; return v.f;
}
__device__ __forceinline__ float lo2f(uint32_t u) {
    union { uint32_t i; float f; } v; v.i = u << 16; return v.f;
}

__global__ void zero_k(int* __restrict__ p, int n) {
    for (int i = blockIdx.x * blockDim.x + threadIdx.x; i < n; i += gridDim.x * blockDim.x)
        p[i] = 0;
}

// ---------------- W prep: bf16 hi/lo split, transposed + 16B-XOR-swizzled ----------------
__global__ void prepW_k(const float* __restrict__ rW, const float* __restrict__ wW,
                        ushort* __restrict__ ws) {
    int i = blockIdx.x * blockDim.x + threadIdx.x;
    if (i >= 6 * 16384) return;
    int m = i >> 14, idx = i & 16383;
    const float* W = (m < 3) ? rW + m * 16384 : wW + (m - 3) * 16384;
    float x = W[idx];
    int k = idx >> 7, c = idx & 127;
    ushort hb = f2bf(x);
    ushort lb = f2bf(x - bf2f(hb));
    int off = ((c * 256 + 2 * k) ^ ((c & 7) << 4)) >> 1;
    ws[(size_t)m * 32768 + off] = hb;
    ws[(size_t)m * 32768 + 16384 + off] = lb;
}

// ---------------- pass 1: bin edges by dst-range, packed (local_dst<<17 | src) -------------
__global__ __launch_bounds__(256) void bucket_k(const int* __restrict__ redge,
                                                const int* __restrict__ wedge,
                                                int* __restrict__ gbcnt,
                                                uint32_t* __restrict__ bpk) {
    __shared__ uint32_t lpk[NRANGE][BINCAP];
    __shared__ int lcnt[NRANGE];
    __shared__ int gbase[NRANGE];
    const int NB = (NEDGE + CHUNK - 1) / CHUNK;
    int bid = blockIdx.x;
    int graph = bid >= NB;
    int cb = graph ? bid - NB : bid;
    const int* eg = graph ? wedge : redge;
    int e0 = cb * CHUNK;
    int nthis = min(CHUNK, NEDGE - e0);
    for (int i = threadIdx.x; i < NRANGE; i += 256) lcnt[i] = 0;
    __syncthreads();
    for (int i = threadIdx.x; i < nthis; i += 256) {
        int s = eg[e0 + i];
        int d = eg[NEDGE + e0 + i];
        int b = d / RSZ;
        uint32_t p = ((uint32_t)(d - b * RSZ) << 17) | (uint32_t)s;
        int slot = atomicAdd(&lcnt[b], 1);
        if (slot < BINCAP) lpk[b][slot] = p;
        else {
            int gs = atomicAdd(&gbcnt[graph * NRANGE + b], 1);
            if (gs < BUCKET_CAP)
                bpk[(size_t)(graph * NRANGE + b) * BUCKET_CAP + gs] = p;
        }
    }
    __syncthreads();
    for (int b = threadIdx.x; b < NRANGE; b += 256) {
        int c = min(lcnt[b], BINCAP);
        lcnt[b] = c;
        gbase[b] = atomicAdd(&gbcnt[graph * NRANGE + b], c);
    }
    __syncthreads();
    for (int b = 0; b < NRANGE; ++b) {
        int c = lcnt[b];
        size_t base = (size_t)(graph * NRANGE + b) * BUCKET_CAP + gbase[b];
        for (int i = threadIdx.x; i < c; i += 256)
            if (gbase[b] + i < BUCKET_CAP) bpk[base + i] = lpk[b][i];
    }
}

// ---------------- pass 2: CSR slice in LDS; src-tile pre-sort then dst counting sort -------
// Extra pass groups each node's edge list by src-tile (src>>12, 18 tiles) so agg waves
// sweep src in ascending order -> chip-wide moving L2 window on the gather target.
__global__ __launch_bounds__(256) void build_k(const uint32_t* __restrict__ bpk,
                                               const int* __restrict__ gbcnt,
                                               int* __restrict__ rp,
                                               int* __restrict__ csr) {
    __shared__ int lcnt[RSZ + 1];
    __shared__ int lexcl[RSZ];
    __shared__ int lcur[RSZ];
    __shared__ int sliceA[BUCKET_CAP];
    __shared__ int sliceB[BUCKET_CAP];
    __shared__ int tcur[64];
    __shared__ int wsum[4];
    __shared__ int s_base, s_carry;
    int combo = blockIdx.x;                 // 0..255
    int graph = combo >> 7, grp = combo & (NRANGE - 1);
    int lo = grp * RSZ;
    int rsize = min(RSZ, NNODE - lo);
    int n = min(gbcnt[combo], BUCKET_CAP);
    const uint32_t* bp = bpk + (size_t)combo * BUCKET_CAP;
    int* rpg = rp + graph * (NNODE + 1);
    int* og = csr + graph * NEDGE;
    int tid = threadIdx.x, lane = tid & 63, wid = tid >> 6;

    if (tid < NRANGE) lcnt[tid] = min(gbcnt[graph * NRANGE + tid], BUCKET_CAP);
    if (tid < 64) tcur[tid] = 0;
    __syncthreads();
    if (tid == 0) {
        int b = 0;
        for (int i = 0; i < grp; ++i) b += lcnt[i];
        s_base = b;
        s_carry = 0;
    }
    __syncthreads();
    // src-tile histogram
    for (int i = tid; i < n; i += 256)
        atomicAdd(&tcur[(bp[i] & 0x1FFFFu) >> 12], 1);
    __syncthreads();
    // exclusive scan of 18 tile bins (wave 0)
    if (wid == 0) {
        int v = (lane < 18) ? tcur[lane] : 0;
        int incl = v;
        #pragma unroll
        for (int off = 1; off < 32; off <<= 1) {
            int t = __shfl_up(incl, off, 64);
            if (lane >= off) incl += t;
        }
        if (lane < 18) tcur[lane] = incl - v;
    }
    __syncthreads();
    // scatter by src-tile -> sliceA (tile-grouped)
    for (int i = tid; i < n; i += 256) {
        uint32_t p = bp[i];
        int t = (p & 0x1FFFFu) >> 12;
        sliceA[atomicAdd(&tcur[t], 1)] = (int)p;
    }
    __syncthreads();
    // dst histogram over sliceA
    for (int i = tid; i < rsize; i += 256) lcnt[i] = 0;
    __syncthreads();
    for (int i = tid; i < n; i += 256)
        atomicAdd(&lcnt[((uint32_t)sliceA[i]) >> 17], 1);
    __syncthreads();
    // exclusive scan over lcnt[0..rsize)
    for (int base = 0; base < rsize; base += 256) {
        int i = base + tid;
        int v = (i < rsize) ? lcnt[i] : 0;
        int incl = v;
        #pragma unroll
        for (int off = 1; off < 64; off <<= 1) {
            int t = __shfl_up(incl, off, 64);
            if (lane >= off) incl += t;
        }
        if (lane == 63) wsum[wid] = incl;
        __syncthreads();
        int carry = s_carry;
        if (wid == 0 && lane < 4) {
            int wv = wsum[lane];
            #pragma unroll
            for (int off = 1; off < 4; off <<= 1) {
                int t = __shfl_up(wv, off, 64);
                if (lane >= off) wv += t;
            }
            wsum[lane] = wv;
        }
        __syncthreads();
        int waveoff = (wid == 0) ? 0 : wsum[wid - 1];
        int excl = carry + waveoff + incl - v;
        if (i < rsize) { lexcl[i] = excl; lcur[i] = excl; }
        __syncthreads();
        if (tid == 0) s_carry = carry + wsum[3];
        __syncthreads();
    }
    int gbas = s_base;
    for (int i = tid; i < rsize; i += 256)
        rpg[lo + i] = gbas + lexcl[i];
    if (grp == NRANGE - 1 && tid == 0) rpg[NNODE] = gbas + n;
    // dst scatter in sliceA order (coarse-stable -> keeps src-tile order per node)
    for (int i = tid; i < n; i += 256) {
        uint32_t p = (uint32_t)sliceA[i];
        int slot = atomicAdd(&lcur[p >> 17], 1);
        sliceB[slot] = (int)(p & 0x1FFFFu);
    }
    __syncthreads();
    for (int i = tid; i < n; i += 256)
        og[gbas + i] = sliceB[i];
}

// ---------------- cvt: featb = bf16([stu; exer])  (shared layer-1 gather array) -----------
__global__ __launch_bounds__(256) void cvt1_k(const float* __restrict__ stu,
                                              const float* __restrict__ exer,
                                              uint4* __restrict__ featb) {
    const int total = NNODE * 16;          // uint4 per row
    for (int i = blockIdx.x * blockDim.x + threadIdx.x; i < total;
         i += gridDim.x * blockDim.x) {
        int node = i >> 4;
        int qq = i & 15;
        const float4* src = (const float4*)((node < S_NUM)
                              ? stu + (size_t)node * KDIM
                              : exer + (size_t)(node - S_NUM) * KDIM);
        float4 a = src[qq * 2];
        float4 b = src[qq * 2 + 1];
        uint4 o;
        o.x = (uint32_t)f2bf(a.x) | ((uint32_t)f2bf(a.y) << 16);
        o.y = (uint32_t)f2bf(a.z) | ((uint32_t)f2bf(a.w) << 16);
        o.z = (uint32_t)f2bf(b.x) | ((uint32_t)f2bf(b.y) << 16);
        o.w = (uint32_t)f2bf(b.z) | ((uint32_t)f2bf(b.w) << 16);
        featb[i] = o;
    }
}

// ---------------- fused aggregation, both graphs ----------------
// useCj=1 (layer 1): gathers shared featb, applies cj[src] via fmaf.
__global__ __launch_bounds__(256) void agg2_k(const uint4* __restrict__ fcR,
                                              const uint4* __restrict__ fcW,
                                              const float* __restrict__ cjR,
                                              const float* __restrict__ cjW,
                                              const int* __restrict__ rp,
                                              const int* __restrict__ csr,
                                              uint4* __restrict__ outR,
                                              uint4* __restrict__ outW,
                                              int useCj) {
    int gn = (blockIdx.x * blockDim.x + threadIdx.x) >> 6;
    if (gn >= 2 * NNODE) return;
    int graph = gn >= NNODE;
    int n = graph ? gn - NNODE : gn;
    const uint4* fc = graph ? fcW : fcR;
    const float* cjg = graph ? cjW : cjR;
    const int* rpg = rp + graph * (NNODE + 1);
    const int* cs = csr + graph * NEDGE;
    uint4* outp = graph ? outW : outR;

    int lane = threadIdx.x & 63;
    int rowgrp = lane >> 4, c16 = lane & 15;
    int beg = rpg[n], end = rpg[n + 1];
    float acc[8];
    #pragma unroll
    for (int j = 0; j < 8; ++j) acc[j] = 0.f;

    if (useCj) {
        for (int e = beg; e < end; e += 8) {
            int r0 = e + rowgrp, r1 = e + 4 + rowgrp;
            int s0 = (r0 < end) ? cs[r0] : -1;
            int s1 = (r1 < end) ? cs[r1] : -1;
            uint4 u0 = {0, 0, 0, 0}, u1 = {0, 0, 0, 0};
            float c0 = 0.f, c1 = 0.f;
            if (s0 >= 0) { u0 = fc[(size_t)s0 * 16 + c16]; c0 = cjg[s0]; }
            if (s1 >= 0) { u1 = fc[(size_t)s1 * 16 + c16]; c1 = cjg[s1]; }
            acc[0] = fmaf(c0, lo2f(u0.x), fmaf(c1, lo2f(u1.x), acc[0]));
            acc[1] = fmaf(c0, hi2f(u0.x), fmaf(c1, hi2f(u1.x), acc[1]));
            acc[2] = fmaf(c0, lo2f(u0.y), fmaf(c1, lo2f(u1.y), acc[2]));
            acc[3] = fmaf(c0, hi2f(u0.y), fmaf(c1, hi2f(u1.y), acc[3]));
            acc[4] = fmaf(c0, lo2f(u0.z), fmaf(c1, lo2f(u1.z), acc[4]));
            acc[5] = fmaf(c0, hi2f(u0.z), fmaf(c1, hi2f(u1.z), acc[5]));
            acc[6] = fmaf(c0, lo2f(u0.w), fmaf(c1, lo2f(u1.w), acc[6]));
            acc[7] = fmaf(c0, hi2f(u0.w), fmaf(c1, hi2f(u1.w), acc[7]));
        }
    } else {
        for (int e = beg; e < end; e += 8) {
            int r0 = e + rowgrp, r1 = e + 4 + rowgrp;
            uint4 u0 = {0, 0, 0, 0}, u1 = {0, 0, 0, 0};
            if (r0 < end) u0 = fc[(size_t)cs[r0] * 16 + c16];
            if (r1 < end) u1 = fc[(size_t)cs[r1] * 16 + c16];
            acc[0] += lo2f(u0.x) + lo2f(u1.x);
            acc[1] += hi2f(u0.x) + hi2f(u1.x);
            acc[2] += lo2f(u0.y) + lo2f(u1.y);
            acc[3] += hi2f(u0.y) + hi2f(u1.y);
            acc[4] += lo2f(u0.z) + lo2f(u1.z);
            acc[5] += hi2f(u0.z) + hi2f(u1.z);
            acc[6] += lo2f(u0.w) + lo2f(u1.w);
            acc[7] += hi2f(u0.w) + hi2f(u1.w);
        }
    }
    #pragma unroll
    for (int j = 0; j < 8; ++j) {
        acc[j] += __shfl_xor(acc[j], 16, 64);
        acc[j] += __shfl_xor(acc[j], 32, 64);
    }
    if (rowgrp == 0) {
        uint4 o;
        o.x = (uint32_t)f2bf(acc[0]) | ((uint32_t)f2bf(acc[1]) << 16);
        o.y = (uint32_t)f2bf(acc[2]) | ((uint32_t)f2bf(acc[3]) << 16);
        o.z = (uint32_t)f2bf(acc[4]) | ((uint32_t)f2bf(acc[5]) << 16);
        o.w = (uint32_t)f2bf(acc[6]) | ((uint32_t)f2bf(acc[7]) << 16);
        outp[(size_t)n * 16 + c16] = o;
    }
}

// ---------------- fused GEMM, both graphs, 256 rows/block ----------------
// Wave owns 64 rows (4 tiles of 16); B-fragments shared across the 4 tiles
// (8 ds_read_b128 : 32 MFMA per col-block); W staged once per 256 rows.
__global__ __launch_bounds__(256) void gemm2_k(const ushort* __restrict__ AR,
                                               const ushort* __restrict__ AW,
                                               const ushort* __restrict__ wsR,
                                               const ushort* __restrict__ wsW,
                                               const float* __restrict__ rci,
                                               const float* __restrict__ rcj,
                                               const float* __restrict__ wci,
                                               const float* __restrict__ wcj,
                                               ushort* __restrict__ outR,
                                               ushort* __restrict__ outW,
                                               int mode) {
    const int halfBlocks = (NNODE + GR - 1) / GR;
    int graph = blockIdx.x >= halfBlocks;
    int bb = graph ? blockIdx.x - halfBlocks : blockIdx.x;
    const ushort* A = graph ? AW : AR;
    const ushort* wsm = graph ? wsW : wsR;
    const float* ci = graph ? wci : rci;
    const float* cj = graph ? wcj : rcj;
    ushort* outB = graph ? outW : outR;

    __shared__ ushort wt[32768];   // 64 KB: hi + lo plane, pre-swizzled
    {
        const uint4* g = (const uint4*)wsm;
        uint4* l = (uint4*)wt;
        for (int i = threadIdx.x; i < 4096; i += 256) l[i] = g[i];
    }
    __syncthreads();

    int wid = threadIdx.x >> 6, lane = threadIdx.x & 63;
    int q = lane >> 4, l16 = lane & 15;
    int rbase = bb * GR + wid * 64;

    short8 z8 = {0, 0, 0, 0, 0, 0, 0, 0};
    short8 afr[4][4];
    #pragma unroll
    for (int t = 0; t < 4; ++t) {
        int row = rbase + t * 16 + l16;
        bool rok = row < NNODE;
        const short8* ar = (const short8*)(A + (size_t)row * KDIM);
        #pragma unroll
        for (int kb = 0; kb < 4; ++kb)
            afr[t][kb] = rok ? ar[kb * 4 + q] : z8;
    }
    float scal[4][4];
    #pragma unroll
    for (int t = 0; t < 4; ++t)
        #pragma unroll
        for (int b = 0; b < 4; ++b) {
            int r = rbase + t * 16 + q * 4 + b;
            scal[t][b] = (r < NNODE) ? (mode ? ci[r] * cj[r] : ci[r]) : 0.f;
        }

    #pragma unroll
    for (int cb = 0; cb < 8; ++cb) {
        int c = cb * 16 + l16;
        short8 bHi[4], bLo[4];
        #pragma unroll
        for (int kb = 0; kb < 4; ++kb) {
            int byte = (c * 256 + 2 * (kb * 32 + q * 8)) ^ ((c & 7) << 4);
            bHi[kb] = *(const short8*)((const char*)wt + byte);
            bLo[kb] = *(const short8*)((const char*)wt + 32768 + byte);
        }
        #pragma unroll
        for (int t = 0; t < 4; ++t) {
            f32x4 acc = {0.f, 0.f, 0.f, 0.f};
            #pragma unroll
            for (int kb = 0; kb < 4; ++kb) {
                acc = __builtin_amdgcn_mfma_f32_16x16x32_bf16(afr[t][kb], bHi[kb], acc, 0, 0, 0);
                acc = __builtin_amdgcn_mfma_f32_16x16x32_bf16(afr[t][kb], bLo[kb], acc, 0, 0, 0);
            }
            #pragma unroll
            for (int b = 0; b < 4; ++b) {
                int r = rbase + t * 16 + q * 4 + b;
                if (r < NNODE)
                    outB[(size_t)r * KDIM + c] = f2bf(acc[b] * scal[t][b]);
            }
        }
    }
}

// ---------------- output assembly (w1/w2 bf16 -> f32 out) ----------------
__global__ void out_k(const ushort* __restrict__ w1, const ushort* __restrict__ w2,
                      const float* __restrict__ disc, const float* __restrict__ kn,
                      const int* __restrict__ sid, const int* __restrict__ eid,
                      float* __restrict__ out) {
    const int total = 2 * BATCH * KDIM + BATCH + KDIM * KDIM;
    for (int i = blockIdx.x * blockDim.x + threadIdx.x; i < total;
         i += gridDim.x * blockDim.x) {
        if (i < BATCH * KDIM) {
            int b = i >> 7, c = i & 127;
            size_t n = (size_t)sid[b];
            out[i] = bf2f(w1[n * KDIM + c]) + bf2f(w2[n * KDIM + c]);
        } else if (i < 2 * BATCH * KDIM) {
            int j = i - BATCH * KDIM;
            int b = j >> 7, c = j & 127;
            size_t n = (size_t)(S_NUM + eid[b]);
            out[i] = bf2f(w1[n * KDIM + c]) + bf2f(w2[n * KDIM + c]);
        } else if (i < 2 * BATCH * KDIM + BATCH) {
            out[i] = disc[eid[i - 2 * BATCH * KDIM]];
        } else {
            out[i] = kn[i - (2 * BATCH * KDIM + BATCH)];
        }
    }
}

static inline size_t align_up(size_t x) { return (x + 255) & ~(size_t)255; }

extern "C" void kernel_launch(void* const* d_in, const int* in_sizes, int n_in,
                              void* d_out, int out_size, void* d_ws, size_t ws_size,
                              hipStream_t stream) {
    const float* stu  = (const float*)d_in[0];
    const float* exer = (const float*)d_in[1];
    const float* kn   = (const float*)d_in[2];
    const float* disc = (const float*)d_in[3];
    const float* rW   = (const float*)d_in[4];
    const float* wW   = (const float*)d_in[5];
    const float* rci  = (const float*)d_in[6];
    const float* rcj  = (const float*)d_in[7];
    const float* wci  = (const float*)d_in[8];
    const float* wcj  = (const float*)d_in[9];
    const int* redge   = (const int*)d_in[10];
    const int* wedge   = (const int*)d_in[11];
    const int* sid     = (const int*)d_in[12];
    const int* eid     = (const int*)d_in[13];
    float* out         = (float*)d_out;

    char* p = (char*)d_ws;
    const size_t fB16 = align_up((size_t)NNODE * KDIM * 2);   // 17.92 MB
    ushort* featb = (ushort*)p; p += fB16;  // shared bf16 features (layer-1 gather)
    ushort* fcR = (ushort*)p; p += fB16;    // per-graph premult; also w1
    ushort* fcW = (ushort*)p; p += fB16;    // also w2
    ushort* pR  = (ushort*)p; p += fB16;    // agg out; aliases buckets pre-agg
    ushort* pW  = (ushort*)p; p += fB16;
    ushort* ws  = (ushort*)p; p += align_up((size_t)6 * 32768 * 2);   // 384 KB
    int* gbcnt = (int*)p; p += align_up((size_t)256 * 4);
    int* rp  = (int*)p; p += align_up((size_t)2 * (NNODE + 1) * 4);
    int* csr = (int*)p; p += align_up((size_t)2 * NEDGE * 4);
    // buckets alias pR (256 x 8448 x 4B = 8.65 MB < 17.92 MB); consumed by
    // build_k before agg2 writes pR.
    uint32_t* bpk = (uint32_t*)pR;

    const int gemmBlocks2 = 2 * ((NNODE + GR - 1) / GR);
    const int aggBlocks2 = (2 * NNODE * 64) / 256;
    const int NB = (NEDGE + CHUNK - 1) / CHUNK;

    // ---- shared prep ----
    prepW_k<<<(6 * 16384 + 255) / 256, 256, 0, stream>>>(rW, wW, ws);
    zero_k<<<1, 256, 0, stream>>>(gbcnt, 256);
    bucket_k<<<2 * NB, 256, 0, stream>>>(redge, wedge, gbcnt, bpk);
    build_k<<<256, 256, 0, stream>>>(bpk, gbcnt, rp, csr);
    cvt1_k<<<2048, 256, 0, stream>>>(stu, exer, (uint4*)featb);

    // ---- 3 layers, both graphs fused per dispatch ----
    agg2_k<<<aggBlocks2, 256, 0, stream>>>((const uint4*)featb, (const uint4*)featb,
                                           rcj, wcj, rp, csr, (uint4*)pR, (uint4*)pW, 1);
    gemm2_k<<<gemmBlocks2, 256, 0, stream>>>(pR, pW, ws + 0 * 32768, ws + 3 * 32768,
                                             rci, rcj, wci, wcj, fcR, fcW, 1);
    agg2_k<<<aggBlocks2, 256, 0, stream>>>((const uint4*)fcR, (const uint4*)fcW,
                                           nullptr, nullptr, rp, csr, (uint4*)pR, (uint4*)pW, 0);
    gemm2_k<<<gemmBlocks2, 256, 0, stream>>>(pR, pW, ws + 1 * 32768, ws + 4 * 32768,
                                             rci, rcj, wci, wcj, fcR, fcW, 1);
    agg2_k<<<aggBlocks2, 256, 0, stream>>>((const uint4*)fcR, (const uint4*)fcW,
                                           nullptr, nullptr, rp, csr, (uint4*)pR, (uint4*)pW, 0);
    gemm2_k<<<gemmBlocks2, 256, 0, stream>>>(pR, pW, ws + 2 * 32768, ws + 5 * 32768,
                                             rci, rcj, wci, wcj, fcR, fcW, 0);

    out_k<<<2048, 256, 0, stream>>>(fcR, fcW, disc, kn, sid, eid, out);
}

// Round 9
// 393.707 us; speedup vs baseline: 3.0656x; 1.0527x over previous
//
#include <hip/hip_runtime.h>
#include <hip/hip_bf16.h>
#include <stdint.h>

#define S_NUM 50000
#define E_NUM 20000
#define NNODE 70000
#define KDIM 128
#define BATCH 8192
#define NEDGE 1000000

#define NRANGE 128            // dst-ranges per graph
#define RSZ 547               // ceil(NNODE / NRANGE)
#define BUCKET_CAP 8448       // per-bucket capacity (mean 7813, sigma 88)
#define RCAP 16672            // per-range padded csr region (>= 8448 + 547*15)
#define CHUNK 8192            // edges per bucket_k block
#define BINCAP 120            // LDS bin capacity
#define GR 256                // gemm rows per block

typedef __attribute__((ext_vector_type(8))) short short8;
typedef __attribute__((ext_vector_type(4))) float f32x4;
typedef __attribute__((ext_vector_type(2))) float f32x2;

__device__ __forceinline__ float bf2f(ushort u) {
    union { uint32_t i; float f; } v; v.i = ((uint32_t)u) << 16; return v.f;
}
__device__ __forceinline__ ushort f2bf(float f) {
    union { uint32_t i; float f; } v; v.f = f;
    uint32_t r = v.i + 0x7fffu + ((v.i >> 16) & 1u);
    return (ushort)(r >> 16);
}
// unpack 2 bf16 (packed in uint32) -> f32x2 {lo, hi}
__device__ __forceinline__ f32x2 up2(uint32_t u) {
    union { uint32_t i; float f; } lo, hi;
    lo.i = u << 16; hi.i = u & 0xffff0000u;
    f32x2 r; r.x = lo.f; r.y = hi.f; return r;
}

// ---------------- W prep (+ gbcnt zero): bf16 hi/lo split, swizzled ----------------
__global__ void prepW_k(const float* __restrict__ rW, const float* __restrict__ wW,
                        ushort* __restrict__ ws, int* __restrict__ gbcnt) {
    if (blockIdx.x == 0 && threadIdx.x < 256) gbcnt[threadIdx.x] = 0;
    int i = blockIdx.x * blockDim.x + threadIdx.x;
    if (i >= 6 * 16384) return;
    int m = i >> 14, idx = i & 16383;
    const float* W = (m < 3) ? rW + m * 16384 : wW + (m - 3) * 16384;
    float x = W[idx];
    int k = idx >> 7, c = idx & 127;
    ushort hb = f2bf(x);
    ushort lb = f2bf(x - bf2f(hb));
    int off = ((c * 256 + 2 * k) ^ ((c & 7) << 4)) >> 1;
    ws[(size_t)m * 32768 + off] = hb;
    ws[(size_t)m * 32768 + 16384 + off] = lb;
}

// ---------------- pass 1: bin edges by dst-range, packed (local_dst<<17 | src) -------------
__global__ __launch_bounds__(256) void bucket_k(const int* __restrict__ redge,
                                                const int* __restrict__ wedge,
                                                int* __restrict__ gbcnt,
                                                uint32_t* __restrict__ bpk) {
    __shared__ uint32_t lpk[NRANGE][BINCAP];
    __shared__ int lcnt[NRANGE];
    __shared__ int gbase[NRANGE];
    const int NB = (NEDGE + CHUNK - 1) / CHUNK;
    int bid = blockIdx.x;
    int graph = bid >= NB;
    int cb = graph ? bid - NB : bid;
    const int* eg = graph ? wedge : redge;
    int e0 = cb * CHUNK;
    int nthis = min(CHUNK, NEDGE - e0);
    for (int i = threadIdx.x; i < NRANGE; i += 256) lcnt[i] = 0;
    __syncthreads();
    for (int i = threadIdx.x; i < nthis; i += 256) {
        int s = eg[e0 + i];
        int d = eg[NEDGE + e0 + i];
        int b = d / RSZ;
        uint32_t p = ((uint32_t)(d - b * RSZ) << 17) | (uint32_t)s;
        int slot = atomicAdd(&lcnt[b], 1);
        if (slot < BINCAP) lpk[b][slot] = p;
        else {
            int gs = atomicAdd(&gbcnt[graph * NRANGE + b], 1);
            if (gs < BUCKET_CAP)
                bpk[(size_t)(graph * NRANGE + b) * BUCKET_CAP + gs] = p;
        }
    }
    __syncthreads();
    for (int b = threadIdx.x; b < NRANGE; b += 256) {
        int c = min(lcnt[b], BINCAP);
        lcnt[b] = c;
        gbase[b] = atomicAdd(&gbcnt[graph * NRANGE + b], c);
    }
    __syncthreads();
    for (int b = 0; b < NRANGE; ++b) {
        int c = lcnt[b];
        size_t base = (size_t)(graph * NRANGE + b) * BUCKET_CAP + gbase[b];
        for (int i = threadIdx.x; i < c; i += 256)
            if (gbase[b] + i < BUCKET_CAP) bpk[base + i] = lpk[b][i];
    }
}

// ---------------- pass 2: CSR slice in LDS, 16-padded rows, fixed per-combo regions --------
// Rows padded to multiple of 16 with sentinel src NNODE (zero feature row) -> agg inner
// loop has no bounds checks. rpb/rpe hold absolute csr offsets (regions are disjoint).
__global__ __launch_bounds__(256) void build_k(const uint32_t* __restrict__ bpk,
                                               const int* __restrict__ gbcnt,
                                               int* __restrict__ rpb,
                                               int* __restrict__ rpe,
                                               int* __restrict__ csr) {
    __shared__ int lcnt[RSZ];
    __shared__ int lexcl[RSZ];
    __shared__ int pexcl[RSZ];
    __shared__ int lcur[RSZ];
    __shared__ int sliceB[BUCKET_CAP];
    __shared__ int wsum[4];
    __shared__ int s_carry;
    int combo = blockIdx.x;                 // 0..255
    int graph = combo >> 7, grp = combo & (NRANGE - 1);
    int lo = grp * RSZ;
    int rsize = min(RSZ, NNODE - lo);
    int n = min(gbcnt[combo], BUCKET_CAP);
    const uint32_t* bp = bpk + (size_t)combo * BUCKET_CAP;
    int* rpbg = rpb + graph * NNODE;
    int* rpeg = rpe + graph * NNODE;
    int* og = csr + (size_t)combo * RCAP;
    const int rbase = combo * RCAP;
    int tid = threadIdx.x, lane = tid & 63, wid = tid >> 6;

    for (int i = tid; i < rsize; i += 256) lcnt[i] = 0;
    if (tid == 0) s_carry = 0;
    __syncthreads();
    // dst histogram
    for (int i = tid; i < n; i += 256)
        atomicAdd(&lcnt[bp[i] >> 17], 1);
    __syncthreads();
    // scan 1: real counts -> lexcl (slice placement)
    for (int base = 0; base < rsize; base += 256) {
        int i = base + tid;
        int v = (i < rsize) ? lcnt[i] : 0;
        int incl = v;
        #pragma unroll
        for (int off = 1; off < 64; off <<= 1) {
            int t = __shfl_up(incl, off, 64);
            if (lane >= off) incl += t;
        }
        if (lane == 63) wsum[wid] = incl;
        __syncthreads();
        int carry = s_carry;
        if (wid == 0 && lane < 4) {
            int wv = wsum[lane];
            #pragma unroll
            for (int off = 1; off < 4; off <<= 1) {
                int t = __shfl_up(wv, off, 64);
                if (lane >= off) wv += t;
            }
            wsum[lane] = wv;
        }
        __syncthreads();
        int waveoff = (wid == 0) ? 0 : wsum[wid - 1];
        int excl = carry + waveoff + incl - v;
        if (i < rsize) { lexcl[i] = excl; lcur[i] = excl; }
        __syncthreads();
        if (tid == 0) s_carry = carry + wsum[3];
        __syncthreads();
    }
    if (tid == 0) s_carry = 0;
    __syncthreads();
    // scan 2: padded counts -> pexcl (global placement)
    for (int base = 0; base < rsize; base += 256) {
        int i = base + tid;
        int v = (i < rsize) ? ((lcnt[i] + 15) & ~15) : 0;
        int incl = v;
        #pragma unroll
        for (int off = 1; off < 64; off <<= 1) {
            int t = __shfl_up(incl, off, 64);
            if (lane >= off) incl += t;
        }
        if (lane == 63) wsum[wid] = incl;
        __syncthreads();
        int carry = s_carry;
        if (wid == 0 && lane < 4) {
            int wv = wsum[lane];
            #pragma unroll
            for (int off = 1; off < 4; off <<= 1) {
                int t = __shfl_up(wv, off, 64);
                if (lane >= off) wv += t;
            }
            wsum[lane] = wv;
        }
        __syncthreads();
        int waveoff = (wid == 0) ? 0 : wsum[wid - 1];
        int excl = carry + waveoff + incl - v;
        if (i < rsize) pexcl[i] = excl;
        __syncthreads();
        if (tid == 0) s_carry = carry + wsum[3];
        __syncthreads();
    }
    // rpb/rpe (padded spans)
    for (int i = tid; i < rsize; i += 256) {
        int pc = (lcnt[i] + 15) & ~15;
        rpbg[lo + i] = rbase + pexcl[i];
        rpeg[lo + i] = rbase + pexcl[i] + pc;
    }
    // dst counting-sort scatter into LDS (keep packed value)
    for (int i = tid; i < n; i += 256) {
        uint32_t p = bp[i];
        int slot = atomicAdd(&lcur[p >> 17], 1);
        sliceB[slot] = (int)p;
    }
    __syncthreads();
    // dense emission of real edges at padded offsets
    for (int i = tid; i < n; i += 256) {
        uint32_t p = (uint32_t)sliceB[i];
        int r = p >> 17;
        og[pexcl[r] + (i - lexcl[r])] = (int)(p & 0x1FFFFu);
    }
    // sentinel tail fill
    for (int r = tid; r < rsize; r += 256) {
        int c = lcnt[r], pc = (c + 15) & ~15, b = pexcl[r];
        for (int j = c; j < pc; ++j) og[b + j] = NNODE;
    }
}

// ---------------- cvt: featb = bf16([stu; exer]) + zero rows + padded cj copies ------------
__global__ __launch_bounds__(256) void cvt1_k(const float* __restrict__ stu,
                                              const float* __restrict__ exer,
                                              const float* __restrict__ rcj,
                                              const float* __restrict__ wcj,
                                              uint4* __restrict__ featb,
                                              uint4* __restrict__ fcR,
                                              uint4* __restrict__ fcW,
                                              float* __restrict__ cjpR,
                                              float* __restrict__ cjpW) {
    const int main = NNODE * 16;           // uint4 per row
    const int total = main + 48 + 2 * (NNODE + 1);
    const uint4 z4 = {0, 0, 0, 0};
    for (int i = blockIdx.x * blockDim.x + threadIdx.x; i < total;
         i += gridDim.x * blockDim.x) {
        if (i < main) {
            int node = i >> 4;
            int qq = i & 15;
            const float4* src = (const float4*)((node < S_NUM)
                                  ? stu + (size_t)node * KDIM
                                  : exer + (size_t)(node - S_NUM) * KDIM);
            float4 a = src[qq * 2];
            float4 b = src[qq * 2 + 1];
            uint4 o;
            o.x = (uint32_t)f2bf(a.x) | ((uint32_t)f2bf(a.y) << 16);
            o.y = (uint32_t)f2bf(a.z) | ((uint32_t)f2bf(a.w) << 16);
            o.z = (uint32_t)f2bf(b.x) | ((uint32_t)f2bf(b.y) << 16);
            o.w = (uint32_t)f2bf(b.z) | ((uint32_t)f2bf(b.w) << 16);
            featb[i] = o;
        } else if (i < main + 48) {
            int j = i - main;
            if (j < 16)      featb[(size_t)NNODE * 16 + j] = z4;        // sentinel rows
            else if (j < 32) fcR[(size_t)NNODE * 16 + (j - 16)] = z4;
            else             fcW[(size_t)NNODE * 16 + (j - 32)] = z4;
        } else {
            int k = i - main - 48;
            if (k <= NNODE)  cjpR[k] = (k < NNODE) ? rcj[k] : 0.f;
            else {
                int m = k - (NNODE + 1);
                cjpW[m] = (m < NNODE) ? wcj[m] : 0.f;
            }
        }
    }
}

// ---------------- fused aggregation, both graphs ----------------
// 16-padded rows: no bounds checks. 16 edges/iter, 4 row-loads in flight.
// f32x2 accumulators -> v_pk_add_f32 / v_pk_fma_f32.
__global__ __launch_bounds__(256) void agg2_k(const uint4* __restrict__ fcR,
                                              const uint4* __restrict__ fcW,
                                              const float* __restrict__ cjR,
                                              const float* __restrict__ cjW,
                                              const int* __restrict__ rpb,
                                              const int* __restrict__ rpe,
                                              const int* __restrict__ csr,
                                              uint4* __restrict__ outR,
                                              uint4* __restrict__ outW,
                                              int useCj) {
    int gn = (blockIdx.x * blockDim.x + threadIdx.x) >> 6;
    if (gn >= 2 * NNODE) return;
    int graph = gn >= NNODE;
    int n = graph ? gn - NNODE : gn;
    const uint4* fc = graph ? fcW : fcR;
    const float* cjg = graph ? cjW : cjR;
    const int* rpbg = rpb + graph * NNODE;
    const int* rpeg = rpe + graph * NNODE;
    uint4* outp = graph ? outW : outR;

    int lane = threadIdx.x & 63;
    int rowgrp = lane >> 4, c16 = lane & 15;
    int beg = rpbg[n], end = rpeg[n];
    f32x2 acc0 = {0.f, 0.f}, acc1 = {0.f, 0.f}, acc2v = {0.f, 0.f}, acc3 = {0.f, 0.f};

    if (useCj) {
        for (int e = beg; e < end; e += 16) {
            int s0 = csr[e + rowgrp];
            int s1 = csr[e + 4 + rowgrp];
            int s2 = csr[e + 8 + rowgrp];
            int s3 = csr[e + 12 + rowgrp];
            uint4 u0 = fc[(size_t)s0 * 16 + c16];
            uint4 u1 = fc[(size_t)s1 * 16 + c16];
            uint4 u2 = fc[(size_t)s2 * 16 + c16];
            uint4 u3 = fc[(size_t)s3 * 16 + c16];
            float c0 = cjg[s0], c1 = cjg[s1], c2 = cjg[s2], c3 = cjg[s3];
            f32x2 v0 = {c0, c0}, v1 = {c1, c1}, v2 = {c2, c2}, v3 = {c3, c3};
            acc0 += v0 * up2(u0.x) + v1 * up2(u1.x) + v2 * up2(u2.x) + v3 * up2(u3.x);
            acc1 += v0 * up2(u0.y) + v1 * up2(u1.y) + v2 * up2(u2.y) + v3 * up2(u3.y);
            acc2v += v0 * up2(u0.z) + v1 * up2(u1.z) + v2 * up2(u2.z) + v3 * up2(u3.z);
            acc3 += v0 * up2(u0.w) + v1 * up2(u1.w) + v2 * up2(u2.w) + v3 * up2(u3.w);
        }
    } else {
        for (int e = beg; e < end; e += 16) {
            int s0 = csr[e + rowgrp];
            int s1 = csr[e + 4 + rowgrp];
            int s2 = csr[e + 8 + rowgrp];
            int s3 = csr[e + 12 + rowgrp];
            uint4 u0 = fc[(size_t)s0 * 16 + c16];
            uint4 u1 = fc[(size_t)s1 * 16 + c16];
            uint4 u2 = fc[(size_t)s2 * 16 + c16];
            uint4 u3 = fc[(size_t)s3 * 16 + c16];
            acc0 += (up2(u0.x) + up2(u1.x)) + (up2(u2.x) + up2(u3.x));
            acc1 += (up2(u0.y) + up2(u1.y)) + (up2(u2.y) + up2(u3.y));
            acc2v += (up2(u0.z) + up2(u1.z)) + (up2(u2.z) + up2(u3.z));
            acc3 += (up2(u0.w) + up2(u1.w)) + (up2(u2.w) + up2(u3.w));
        }
    }
    float a[8] = {acc0.x, acc0.y, acc1.x, acc1.y, acc2v.x, acc2v.y, acc3.x, acc3.y};
    #pragma unroll
    for (int j = 0; j < 8; ++j) {
        a[j] += __shfl_xor(a[j], 16, 64);
        a[j] += __shfl_xor(a[j], 32, 64);
    }
    if (rowgrp == 0) {
        uint4 o;
        o.x = (uint32_t)f2bf(a[0]) | ((uint32_t)f2bf(a[1]) << 16);
        o.y = (uint32_t)f2bf(a[2]) | ((uint32_t)f2bf(a[3]) << 16);
        o.z = (uint32_t)f2bf(a[4]) | ((uint32_t)f2bf(a[5]) << 16);
        o.w = (uint32_t)f2bf(a[6]) | ((uint32_t)f2bf(a[7]) << 16);
        outp[(size_t)n * 16 + c16] = o;
    }
}

// ---------------- fused GEMM, both graphs, 256 rows/block ----------------
__global__ __launch_bounds__(256) void gemm2_k(const ushort* __restrict__ AR,
                                               const ushort* __restrict__ AW,
                                               const ushort* __restrict__ wsR,
                                               const ushort* __restrict__ wsW,
                                               const float* __restrict__ rci,
                                               const float* __restrict__ rcj,
                                               const float* __restrict__ wci,
                                               const float* __restrict__ wcj,
                                               ushort* __restrict__ outR,
                                               ushort* __restrict__ outW,
                                               int mode) {
    const int halfBlocks = (NNODE + GR - 1) / GR;
    int graph = blockIdx.x >= halfBlocks;
    int bb = graph ? blockIdx.x - halfBlocks : blockIdx.x;
    const ushort* A = graph ? AW : AR;
    const ushort* wsm = graph ? wsW : wsR;
    const float* ci = graph ? wci : rci;
    const float* cj = graph ? wcj : rcj;
    ushort* outB = graph ? outW : outR;

    __shared__ ushort wt[32768];   // 64 KB: hi + lo plane, pre-swizzled
    {
        const uint4* g = (const uint4*)wsm;
        uint4* l = (uint4*)wt;
        for (int i = threadIdx.x; i < 4096; i += 256) l[i] = g[i];
    }
    __syncthreads();

    int wid = threadIdx.x >> 6, lane = threadIdx.x & 63;
    int q = lane >> 4, l16 = lane & 15;
    int rbase = bb * GR + wid * 64;

    short8 z8 = {0, 0, 0, 0, 0, 0, 0, 0};
    short8 afr[4][4];
    #pragma unroll
    for (int t = 0; t < 4; ++t) {
        int row = rbase + t * 16 + l16;
        bool rok = row < NNODE;
        const short8* ar = (const short8*)(A + (size_t)row * KDIM);
        #pragma unroll
        for (int kb = 0; kb < 4; ++kb)
            afr[t][kb] = rok ? ar[kb * 4 + q] : z8;
    }
    float scal[4][4];
    #pragma unroll
    for (int t = 0; t < 4; ++t)
        #pragma unroll
        for (int b = 0; b < 4; ++b) {
            int r = rbase + t * 16 + q * 4 + b;
            scal[t][b] = (r < NNODE) ? (mode ? ci[r] * cj[r] : ci[r]) : 0.f;
        }

    #pragma unroll
    for (int cb = 0; cb < 8; ++cb) {
        int c = cb * 16 + l16;
        short8 bHi[4], bLo[4];
        #pragma unroll
        for (int kb = 0; kb < 4; ++kb) {
            int byte = (c * 256 + 2 * (kb * 32 + q * 8)) ^ ((c & 7) << 4);
            bHi[kb] = *(const short8*)((const char*)wt + byte);
            bLo[kb] = *(const short8*)((const char*)wt + 32768 + byte);
        }
        #pragma unroll
        for (int t = 0; t < 4; ++t) {
            f32x4 acc = {0.f, 0.f, 0.f, 0.f};
            #pragma unroll
            for (int kb = 0; kb < 4; ++kb) {
                acc = __builtin_amdgcn_mfma_f32_16x16x32_bf16(afr[t][kb], bHi[kb], acc, 0, 0, 0);
                acc = __builtin_amdgcn_mfma_f32_16x16x32_bf16(afr[t][kb], bLo[kb], acc, 0, 0, 0);
            }
            #pragma unroll
            for (int b = 0; b < 4; ++b) {
                int r = rbase + t * 16 + q * 4 + b;
                if (r < NNODE)
                    outB[(size_t)r * KDIM + c] = f2bf(acc[b] * scal[t][b]);
            }
        }
    }
}

// ---------------- output assembly (w1/w2 bf16 -> f32 out) ----------------
__global__ void out_k(const ushort* __restrict__ w1, const ushort* __restrict__ w2,
                      const float* __restrict__ disc, const float* __restrict__ kn,
                      const int* __restrict__ sid, const int* __restrict__ eid,
                      float* __restrict__ out) {
    const int total = 2 * BATCH * KDIM + BATCH + KDIM * KDIM;
    for (int i = blockIdx.x * blockDim.x + threadIdx.x; i < total;
         i += gridDim.x * blockDim.x) {
        if (i < BATCH * KDIM) {
            int b = i >> 7, c = i & 127;
            size_t n = (size_t)sid[b];
            out[i] = bf2f(w1[n * KDIM + c]) + bf2f(w2[n * KDIM + c]);
        } else if (i < 2 * BATCH * KDIM) {
            int j = i - BATCH * KDIM;
            int b = j >> 7, c = j & 127;
            size_t n = (size_t)(S_NUM + eid[b]);
            out[i] = bf2f(w1[n * KDIM + c]) + bf2f(w2[n * KDIM + c]);
        } else if (i < 2 * BATCH * KDIM + BATCH) {
            out[i] = disc[eid[i - 2 * BATCH * KDIM]];
        } else {
            out[i] = kn[i - (2 * BATCH * KDIM + BATCH)];
        }
    }
}

static inline size_t align_up(size_t x) { return (x + 255) & ~(size_t)255; }

extern "C" void kernel_launch(void* const* d_in, const int* in_sizes, int n_in,
                              void* d_out, int out_size, void* d_ws, size_t ws_size,
                              hipStream_t stream) {
    const float* stu  = (const float*)d_in[0];
    const float* exer = (const float*)d_in[1];
    const float* kn   = (const float*)d_in[2];
    const float* disc = (const float*)d_in[3];
    const float* rW   = (const float*)d_in[4];
    const float* wW   = (const float*)d_in[5];
    const float* rci  = (const float*)d_in[6];
    const float* rcj  = (const float*)d_in[7];
    const float* wci  = (const float*)d_in[8];
    const float* wcj  = (const float*)d_in[9];
    const int* redge   = (const int*)d_in[10];
    const int* wedge   = (const int*)d_in[11];
    const int* sid     = (const int*)d_in[12];
    const int* eid     = (const int*)d_in[13];
    float* out         = (float*)d_out;

    char* p = (char*)d_ws;
    const size_t fB16 = align_up((size_t)(NNODE + 1) * KDIM * 2);   // +sentinel row
    ushort* featb = (ushort*)p; p += fB16;  // shared bf16 features (layer-1 gather)
    ushort* fcR = (ushort*)p; p += fB16;    // per-graph premult; also w1
    ushort* fcW = (ushort*)p; p += fB16;    // also w2
    ushort* pR  = (ushort*)p; p += fB16;    // agg out; aliases buckets pre-agg
    ushort* pW  = (ushort*)p; p += fB16;
    ushort* ws  = (ushort*)p; p += align_up((size_t)6 * 32768 * 2);   // 384 KB
    int* gbcnt = (int*)p; p += align_up((size_t)256 * 4);
    int* rpb = (int*)p; p += align_up((size_t)2 * NNODE * 4);
    int* rpe = (int*)p; p += align_up((size_t)2 * NNODE * 4);
    int* csr = (int*)p; p += align_up((size_t)256 * RCAP * 4);
    float* cjpR = (float*)p; p += align_up((size_t)(NNODE + 1) * 4);
    float* cjpW = (float*)p; p += align_up((size_t)(NNODE + 1) * 4);
    // buckets alias pR (256 x 8448 x 4B = 8.65 MB < 17.92 MB); consumed by
    // build_k before agg2 writes pR.
    uint32_t* bpk = (uint32_t*)pR;

    const int gemmBlocks2 = 2 * ((NNODE + GR - 1) / GR);
    const int aggBlocks2 = (2 * NNODE * 64) / 256;
    const int NB = (NEDGE + CHUNK - 1) / CHUNK;

    // ---- shared prep ----
    prepW_k<<<(6 * 16384 + 255) / 256, 256, 0, stream>>>(rW, wW, ws, gbcnt);
    bucket_k<<<2 * NB, 256, 0, stream>>>(redge, wedge, gbcnt, bpk);
    build_k<<<256, 256, 0, stream>>>(bpk, gbcnt, rpb, rpe, csr);
    cvt1_k<<<2048, 256, 0, stream>>>(stu, exer, rcj, wcj, (uint4*)featb,
                                     (uint4*)fcR, (uint4*)fcW, cjpR, cjpW);

    // ---- 3 layers, both graphs fused per dispatch ----
    agg2_k<<<aggBlocks2, 256, 0, stream>>>((const uint4*)featb, (const uint4*)featb,
                                           cjpR, cjpW, rpb, rpe, csr,
                                           (uint4*)pR, (uint4*)pW, 1);
    gemm2_k<<<gemmBlocks2, 256, 0, stream>>>(pR, pW, ws + 0 * 32768, ws + 3 * 32768,
                                             rci, rcj, wci, wcj, fcR, fcW, 1);
    agg2_k<<<aggBlocks2, 256, 0, stream>>>((const uint4*)fcR, (const uint4*)fcW,
                                           nullptr, nullptr, rpb, rpe, csr,
                                           (uint4*)pR, (uint4*)pW, 0);
    gemm2_k<<<gemmBlocks2, 256, 0, stream>>>(pR, pW, ws + 1 * 32768, ws + 4 * 32768,
                                             rci, rcj, wci, wcj, fcR, fcW, 1);
    agg2_k<<<aggBlocks2, 256, 0, stream>>>((const uint4*)fcR, (const uint4*)fcW,
                                           nullptr, nullptr, rpb, rpe, csr,
                                           (uint4*)pR, (uint4*)pW, 0);
    gemm2_k<<<gemmBlocks2, 256, 0, stream>>>(pR, pW, ws + 2 * 32768, ws + 5 * 32768,
                                             rci, rcj, wci, wcj, fcR, fcW, 0);

    out_k<<<2048, 256, 0, stream>>>(fcR, fcW, disc, kn, sid, eid, out);
}